// Round 12
// baseline (299.462 us; speedup 1.0000x reference)
//
#include <hip/hip_runtime.h>

typedef unsigned int u32;
typedef unsigned long long u64;

#define BB 4
#define NN 261888
#define KSEL 6000
#define CAP 8192
#define PC 1000
#define NMS_THR 0.7f
#define NW 94          /* words used */
#define NWP 96         /* padded row stride in words; word 94 = diagonal dup */
#define NR (NW*64)     /* padded mask rows = 6016 */
#define NCH (NR/8)     /* 752 chunks of 8 rows */
#define CHB (8*NWP*8)  /* chunk bytes = 6144 */
#define RING 10        /* LDS ring slots: 10*6144 = 61440 B */
#define COLSPLIT 6

#define HB 31
#define CHUNK_H (NN/HB)
#define HITER (CHUNK_H/256)
#define CB 93
#define CHUNK_C (NN/CB)
#define CITER (CHUNK_C/256)

#if defined(__has_builtin)
#if __has_builtin(__builtin_amdgcn_global_load_lds)
#define HAS_GLL 1
#endif
#endif
#ifndef HAS_GLL
#define HAS_GLL 0
#endif

// ---------------- ws layout (u32 units) ----------------
#define HIST1_OFF 0
#define HIST2_OFF (BB*2048)
#define SEL_OFF   (BB*2048*2)
#define CNT_OFF   (BB*2048*2 + BB*4)
#define ZERO_WORDS (BB*2048*2 + BB*4 + BB*32)

__global__ void k_zero(u32* ws) {
    int i = blockIdx.x * 256 + threadIdx.x;
    if (i < ZERO_WORDS) ws[i] = 0u;
}

__global__ void k_hist1(const float2* __restrict__ probs2, u32* __restrict__ hist1) {
    __shared__ u32 lh[2048];
    int b = blockIdx.y;
    size_t base = (size_t)b * NN + (size_t)blockIdx.x * CHUNK_H;
    for (int j = threadIdx.x; j < 2048; j += 256) lh[j] = 0u;
    __syncthreads();
    #pragma unroll 4
    for (int it = 0; it < HITER; ++it) {
        float2 p = probs2[base + it * 256 + threadIdx.x];
        atomicAdd(&lh[__float_as_uint(p.y) >> 21], 1u);
    }
    __syncthreads();
    for (int j = threadIdx.x; j < 2048; j += 256) {
        u32 c = lh[j];
        if (c) atomicAdd(&hist1[b * 2048 + j], c);
    }
}

__global__ void k_sel1(const u32* __restrict__ hist1, u32* __restrict__ sel) {
    __shared__ u32 gsum[256];
    __shared__ u32 lh[2048];
    int b = blockIdx.x;
    int t = threadIdx.x;
    u32 s = 0;
    #pragma unroll
    for (int j = 0; j < 8; ++j) {
        u32 v = hist1[b * 2048 + 2047 - (t * 8 + j)];
        lh[t * 8 + j] = v;
        s += v;
    }
    gsum[t] = s;
    __syncthreads();
    if (t == 0) {
        u32 cum = 0;
        for (int g = 0; g < 256; ++g) {
            if (cum + gsum[g] >= (u32)KSEL) {
                for (int j = 0; j < 8; ++j) {
                    u32 c = lh[g * 8 + j];
                    if (cum + c >= (u32)KSEL) {
                        sel[b * 4 + 0] = (u32)(2047 - (g * 8 + j));
                        sel[b * 4 + 1] = cum;
                        break;
                    }
                    cum += c;
                }
                break;
            }
            cum += gsum[g];
        }
    }
}

__global__ void k_hist2(const float2* __restrict__ probs2, const u32* __restrict__ sel,
                        u32* __restrict__ hist2) {
    int b = blockIdx.y;
    u32 b1 = sel[b * 4 + 0];
    size_t base = (size_t)b * NN + (size_t)blockIdx.x * CHUNK_H;
    #pragma unroll 4
    for (int it = 0; it < HITER; ++it) {
        float2 p = probs2[base + it * 256 + threadIdx.x];
        u32 key = __float_as_uint(p.y);
        if ((key >> 21) == b1) atomicAdd(&hist2[b * 2048 + ((key >> 10) & 2047u)], 1u);
    }
}

__global__ void k_sel2(const u32* __restrict__ hist2, u32* __restrict__ sel) {
    __shared__ u32 gsum[256];
    __shared__ u32 lh[2048];
    int b = blockIdx.x;
    int t = threadIdx.x;
    u32 s = 0;
    #pragma unroll
    for (int j = 0; j < 8; ++j) {
        u32 v = hist2[b * 2048 + 2047 - (t * 8 + j)];
        lh[t * 8 + j] = v;
        s += v;
    }
    gsum[t] = s;
    __syncthreads();
    if (t == 0) {
        u32 cum = sel[b * 4 + 1];
        u32 b1 = sel[b * 4 + 0];
        for (int g = 0; g < 256; ++g) {
            if (cum + gsum[g] >= (u32)KSEL) {
                for (int j = 0; j < 8; ++j) {
                    cum += lh[g * 8 + j];
                    if (cum >= (u32)KSEL) {
                        sel[b * 4 + 2] = (b1 << 11) | (u32)(2047 - (g * 8 + j));
                        break;
                    }
                }
                break;
            }
            cum += gsum[g];
        }
    }
}

__global__ void k_compact(const float2* __restrict__ probs2, const u32* __restrict__ sel,
                          u32* __restrict__ candCount, u64* __restrict__ cand) {
    __shared__ u32 wsum[4];
    __shared__ u32 blkBase;
    int b = blockIdx.y;
    int tid = threadIdx.x;
    int wave = tid >> 6, lane = tid & 63;
    u32 base = (u32)blockIdx.x * CHUNK_C;
    u32 thr = sel[b * 4 + 2];

    u32 keys[CITER];
    u32 cnt = 0;
    #pragma unroll
    for (int it = 0; it < CITER; ++it) {
        float2 p = probs2[(size_t)b * NN + base + it * 256 + tid];
        u32 key = __float_as_uint(p.y);
        keys[it] = key;
        cnt += ((key >> 10) >= thr) ? 1u : 0u;
    }
    #pragma unroll
    for (int off = 32; off; off >>= 1) cnt += __shfl_down(cnt, off);
    if (lane == 0) wsum[wave] = cnt;
    __syncthreads();
    if (tid == 0) {
        u32 w0 = wsum[0], w1 = wsum[1], w2 = wsum[2], w3 = wsum[3];
        u32 tot = w0 + w1 + w2 + w3;
        wsum[0] = 0; wsum[1] = w0; wsum[2] = w0 + w1; wsum[3] = w0 + w1 + w2;
        blkBase = tot ? atomicAdd(&candCount[b * 32], tot) : 0u;
    }
    __syncthreads();
    u32 run = blkBase + wsum[wave];
    u64* cb = cand + (size_t)b * CAP;
    #pragma unroll
    for (int it = 0; it < CITER; ++it) {
        u32 key = keys[it];
        bool pred = (key >> 10) >= thr;
        u64 m = __ballot(pred);
        if (pred) {
            u32 pos = run + (u32)__popcll(m & ((1ull << lane) - 1ull));
            u32 gi = base + it * 256 + tid;
            if (pos < CAP) cb[pos] = ((u64)key << 32) | (u32)(~gi);
        }
        run += (u32)__popcll(m);
    }
}

__global__ __launch_bounds__(512) void k_rank(const u64* __restrict__ cand,
                                              const u32* __restrict__ candCount,
                                              u64* __restrict__ sorted) {
    __shared__ u64 keys[CAP];
    int b = blockIdx.y;
    int tid = threadIdx.x;
    int cnt = (int)candCount[b * 32];
    if (cnt > CAP) cnt = CAP;
    const u64* cb = cand + (size_t)b * CAP;
    for (int j = tid; j < CAP; j += 512)
        keys[j] = (j < cnt) ? cb[j] : 0ull;
    __syncthreads();
    int r = blockIdx.x * 512 + tid;
    if (r >= cnt) return;
    u64 my = keys[r];
    int cnt16 = (cnt + 15) & ~15;
    int rank = 0;
    for (int j = 0; j < cnt16; j += 16) {
        #pragma unroll
        for (int u = 0; u < 16; ++u)
            rank += (keys[j + u] > my) ? 1 : 0;
    }
    if (rank < KSEL) sorted[(size_t)b * KSEL + rank] = my;
}

__global__ void k_decode(const u64* __restrict__ sorted,
                         const float4* __restrict__ anchors, const float4* __restrict__ deltas,
                         float4* __restrict__ boxes) {
    int b = blockIdx.y;
    int t = blockIdx.x * 256 + threadIdx.x;
    if (t >= KSEL) return;
    u64 sk = sorted[(size_t)b * KSEL + t];
    u32 idx = ~(u32)(sk & 0xFFFFFFFFull);
    if (idx >= NN) idx = NN - 1;
    float4 a = anchors[(size_t)b * NN + idx];
    float4 d = deltas[(size_t)b * NN + idx];
    float dy = __fmul_rn(d.x, 0.1f);
    float dx = __fmul_rn(d.y, 0.1f);
    float dh = __fmul_rn(d.z, 0.2f);
    float dw = __fmul_rn(d.w, 0.2f);
    float h  = __fsub_rn(a.z, a.x);
    float w  = __fsub_rn(a.w, a.y);
    float cy = __fadd_rn(__fadd_rn(a.x, __fmul_rn(0.5f, h)), __fmul_rn(dy, h));
    float cx = __fadd_rn(__fadd_rn(a.y, __fmul_rn(0.5f, w)), __fmul_rn(dx, w));
    float h2 = __fmul_rn(h, expf(dh));
    float w2 = __fmul_rn(w, expf(dw));
    float y1 = __fsub_rn(cy, __fmul_rn(0.5f, h2));
    float x1 = __fsub_rn(cx, __fmul_rn(0.5f, w2));
    float y2 = __fadd_rn(y1, h2);
    float x2 = __fadd_rn(x1, w2);
    y1 = fminf(fmaxf(y1, 0.0f), 1.0f);
    x1 = fminf(fmaxf(x1, 0.0f), 1.0f);
    y2 = fminf(fmaxf(y2, 0.0f), 1.0f);
    x2 = fminf(fmaxf(x2, 0.0f), 1.0f);
    float4 out;
    out.x = y1; out.y = x1; out.z = y2; out.w = x2;
    boxes[(size_t)b * KSEL + t] = out;
}

__global__ void k_sortgather(const u64* __restrict__ cand, const u32* __restrict__ candCount,
                             const float4* __restrict__ anchors, const float4* __restrict__ deltas,
                             float4* __restrict__ boxes) {
    __shared__ u64 s[CAP];
    int b = blockIdx.x;
    int tid = threadIdx.x;
    u32 cnt = candCount[b * 32];
    if (cnt > CAP) cnt = CAP;
    for (int j = tid; j < CAP; j += 1024)
        s[j] = (j < (int)cnt) ? cand[(size_t)b * CAP + j] : 0ull;
    __syncthreads();
    for (int k = 2; k <= CAP; k <<= 1) {
        for (int j = k >> 1; j > 0; j >>= 1) {
            for (int idx = tid; idx < CAP; idx += 1024) {
                int l = idx ^ j;
                if (l > idx) {
                    u64 a = s[idx], c = s[l];
                    bool dir = ((idx & k) == 0);
                    if ((a < c) == dir) { s[idx] = c; s[l] = a; }
                }
            }
            __syncthreads();
        }
    }
    for (int t = tid; t < KSEL; t += 1024) {
        u64 sk = s[t];
        u32 idx = ~(u32)(sk & 0xFFFFFFFFull);
        float4 a = anchors[(size_t)b * NN + idx];
        float4 d = deltas[(size_t)b * NN + idx];
        float dy = __fmul_rn(d.x, 0.1f);
        float dx = __fmul_rn(d.y, 0.1f);
        float dh = __fmul_rn(d.z, 0.2f);
        float dw = __fmul_rn(d.w, 0.2f);
        float h  = __fsub_rn(a.z, a.x);
        float w  = __fsub_rn(a.w, a.y);
        float cy = __fadd_rn(__fadd_rn(a.x, __fmul_rn(0.5f, h)), __fmul_rn(dy, h));
        float cx = __fadd_rn(__fadd_rn(a.y, __fmul_rn(0.5f, w)), __fmul_rn(dx, w));
        float h2 = __fmul_rn(h, expf(dh));
        float w2 = __fmul_rn(w, expf(dw));
        float y1 = __fsub_rn(cy, __fmul_rn(0.5f, h2));
        float x1 = __fsub_rn(cx, __fmul_rn(0.5f, w2));
        float y2 = __fadd_rn(y1, h2);
        float x2 = __fadd_rn(x1, w2);
        y1 = fminf(fmaxf(y1, 0.0f), 1.0f);
        x1 = fminf(fmaxf(x1, 0.0f), 1.0f);
        y2 = fminf(fmaxf(y2, 0.0f), 1.0f);
        x2 = fminf(fmaxf(x2, 0.0f), 1.0f);
        float4 out;
        out.x = y1; out.y = x1; out.z = y2; out.w = x2;
        boxes[(size_t)b * KSEL + t] = out;
    }
}

// ---------- phase 1: upper-triangle bitmask, row stride NWP; diag dup @ word 94 ----------
__global__ __launch_bounds__(256) void k_iou(const float4* __restrict__ boxes,
                                             u64* __restrict__ mask) {
    __shared__ float4 colBox[4][64];
    __shared__ float  colArea[4][64];
    int b = blockIdx.z;
    int rblk = blockIdx.x;
    int r0 = rblk * 64;
    int tid = threadIdx.x;
    int wave = tid >> 6, lane = tid & 63;
    const float4* B4 = boxes + (size_t)b * KSEL;

    int r = r0 + lane;
    float4 rb;
    if (r < KSEL) rb = B4[r];
    else { rb.x = 2.0f; rb.y = 2.0f; rb.z = 3.0f; rb.w = 3.0f; }
    float ra = __fmul_rn(__fsub_rn(rb.z, rb.x), __fsub_rn(rb.w, rb.y));

    const double M0 = 0.5 * ((double)__uint_as_float(0x3F333333u)
                           + (double)__uint_as_float(0x3F333334u));
    u64* Mb = mask + (size_t)b * NR * NWP;

    for (int jw = rblk + blockIdx.y * 4 + wave; jw < NW; jw += 4 * COLSPLIT) {
        int j = jw * 64 + lane;
        float4 cbx;
        if (j < KSEL) cbx = B4[j];
        else { cbx.x = 2.0f; cbx.y = 2.0f; cbx.z = 3.0f; cbx.w = 3.0f; }
        colBox[wave][lane] = cbx;
        colArea[wave][lane] = __fmul_rn(__fsub_rn(cbx.z, cbx.x), __fsub_rn(cbx.w, cbx.y));
        asm volatile("" ::: "memory");

        u64 word = 0ull;
        #pragma unroll
        for (int c = 0; c < 64; ++c) {
            float4 cb = colBox[wave][c];
            float ca = colArea[wave][c];
            float ih = fmaxf(__fsub_rn(fminf(rb.z, cb.z), fmaxf(rb.x, cb.x)), 0.0f);
            float iw = fmaxf(__fsub_rn(fminf(rb.w, cb.w), fmaxf(rb.y, cb.y)), 0.0f);
            float inter = __fmul_rn(ih, iw);
            float denom = __fadd_rn(__fsub_rn(__fadd_rn(ra, ca), inter), 1e-8f);
            bool pred = ((double)inter >= M0 * (double)denom);
            word |= ((u64)pred) << c;
        }
        Mb[(size_t)(r0 + lane) * NWP + jw] = word;
        if (jw == rblk) Mb[(size_t)(r0 + lane) * NWP + 94] = word;  // diag dup
        asm volatile("" ::: "memory");
    }
}

// ---------- phase 2: reduce with LDS ring + global_load_lds deep prefetch ----------
__device__ __forceinline__ u64 readlane64(u64 v, int lane) {
    u32 lo = (u32)__builtin_amdgcn_readlane((int)(u32)v, lane);
    u32 hi = (u32)__builtin_amdgcn_readlane((int)(u32)(v >> 32), lane);
    return ((u64)hi << 32) | (u64)lo;
}

__global__ __launch_bounds__(64) void k_reduce(const u64* __restrict__ mask,
                                               const float4* __restrict__ boxes,
                                               float* __restrict__ outp) {
    __shared__ __align__(16) unsigned char ring[RING * CHB];  // 61440 B
    __shared__ u32 keptIdx[PC];                               // 4000 B
    int b = blockIdx.x;
    int lane = threadIdx.x;
    const u64* M = mask + (size_t)b * NR * NWP;
    const float4* B4 = boxes + (size_t)b * KSEL;
    int lsel = lane < 47 ? lane : 47;   // lanes >=48 duplicate lane47 (inert, broadcast-free)
    u64 rwA = 0ull, rwB = 0ull;         // lane l holds removed-words 2l (A), 2l+1 (B)
    int k = 0, kprev = 0;
    u64 kb;

#define ISSUE(ck, s) do {                                                     \
    int ck_ = (ck); if (ck_ > NCH - 1) ck_ = NCH - 1;                         \
    const unsigned char* g_ = (const unsigned char*)M + (size_t)ck_ * CHB;    \
    unsigned char* l_ = &ring[(s) * CHB];                                     \
    _Pragma("unroll")                                                         \
    for (int i_ = 0; i_ < 6; ++i_) {                                          \
        GLL(g_ + (size_t)i_ * 1024 + (size_t)lane * 16, l_ + i_ * 1024);      \
    }                                                                         \
} while (0)

#if HAS_GLL
#define GLL(gp, lp)                                                           \
    __builtin_amdgcn_global_load_lds(                                         \
        (const __attribute__((address_space(1))) unsigned int*)(gp),          \
        (__attribute__((address_space(3))) unsigned int*)(lp), 16, 0, 0)
#else
#define GLL(gp, lp)                                                           \
    do { *(ulonglong2*)((lp) + lane * 16) = *(const ulonglong2*)(gp); } while (0)
#endif

    // prologue: fill the ring (10 chunks, 60 in-flight ops)
    #pragma unroll
    for (int s = 0; s < RING; ++s) ISSUE(s, s);

    for (int g = 0; g < NW; ++g) {
#if HAS_GLL
        asm volatile("s_waitcnt vmcnt(12)" ::: "memory");  // chunks g*8..g*8+7 arrived
#else
        asm volatile("" ::: "memory");
#endif
        // gather diag: lane l = word94 of row g*64+l (in this group's chunks)
        int sch = (g * 8 + (lane >> 3)) % RING;
        u64 dg = *(const u64*)&ring[(size_t)sch * CHB + (size_t)(lane & 7) * 768 + 752];

        {   // DECIDE(g)
            u64 rem_ = (g & 1) ? readlane64(rwB, g >> 1) : readlane64(rwA, g >> 1);
            int remaining_ = KSEL - g * 64;
            u64 valid_ = (remaining_ >= 64) ? ~0ull : ((remaining_ <= 0) ? 0ull : ((1ull << remaining_) - 1ull));
            u64 todo_ = ~rem_ & valid_;
            kb = 0ull;
            while (todo_ && k < PC) {
                int i_ = (int)__builtin_ctzll(todo_);
                kb |= (1ull << i_);
                ++k;
                u64 drow_ = readlane64(dg, i_);
                todo_ &= ~(drow_ | (1ull << i_));
            }
            if ((kb >> lane) & 1ull) {
                int rank_ = kprev + (int)__popcll(kb & ((1ull << lane) - 1ull));
                keptIdx[rank_] = (u32)(g * 64 + lane);
            }
            kprev = k;
        }
        if (k >= PC) break;

        #pragma unroll
        for (int c = 0; c < 8; ++c) {
            int s = (g * 8 + c) % RING;
            #pragma unroll
            for (int r_ = 0; r_ < 8; ++r_) {
                ulonglong2 v_ = *(const ulonglong2*)&ring[(size_t)s * CHB + (size_t)r_ * 768 + (size_t)lsel * 16];
                if ((kb >> (c * 8 + r_)) & 1ull) { rwA |= v_.x; rwB |= v_.y; }
            }
            ISSUE(g * 8 + c + RING, s);
        }
    }
    __syncthreads();

    float4* O = (float4*)outp + (size_t)b * PC;
    for (int t = lane; t < PC; t += 64) {
        float4 v; v.x = 0.0f; v.y = 0.0f; v.z = 0.0f; v.w = 0.0f;
        if (t < k) v = B4[keptIdx[t]];
        O[t] = v;
    }
#undef ISSUE
#undef GLL
}

// ---------- fallback serial NMS (used only if ws too small for mask) ----------
__global__ void k_nms(const float4* __restrict__ boxes, float* __restrict__ outp) {
    __shared__ float4 chunk[512];
    __shared__ float4 keptBox[PC];
    __shared__ float  keptArea[PC];
    __shared__ u32    flag[2];
    int b = blockIdx.x;
    int tid = threadIdx.x;
    const float4* B4 = boxes + (size_t)b * KSEL;

    if (tid < 2) flag[tid] = 0u;
    for (int j = tid; j < 512; j += 256) chunk[j] = B4[j];
    __syncthreads();

    int kc = 0;
    for (int i = 0; i < KSEL && kc < PC; ++i) {
        int ci = i & 511;
        if (ci == 0 && i != 0) {
            for (int j = tid; j < 512 && (i + j) < KSEL; j += 256) chunk[j] = B4[i + j];
            __syncthreads();
        }
        float4 cb = chunk[ci];
        float careaV = __fmul_rn(__fsub_rn(cb.z, cb.x), __fsub_rn(cb.w, cb.y));
        bool sup = false;
        for (int t = tid; t < kc; t += 256) {
            float4 kb2 = keptBox[t];
            float ih = fmaxf(__fsub_rn(fminf(cb.z, kb2.z), fmaxf(cb.x, kb2.x)), 0.0f);
            float iw = fmaxf(__fsub_rn(fminf(cb.w, kb2.w), fmaxf(cb.y, kb2.y)), 0.0f);
            float inter = __fmul_rn(ih, iw);
            float denom = __fadd_rn(__fsub_rn(__fadd_rn(careaV, keptArea[t]), inter), 1e-8f);
            if (__fdiv_rn(inter, denom) > NMS_THR) sup = true;
        }
        int p = i & 1;
        if (sup) flag[p] = 1u;
        if (tid == 0) flag[p ^ 1] = 0u;
        __syncthreads();
        if (flag[p] == 0u) {
            if (tid == 0) { keptBox[kc] = cb; keptArea[kc] = careaV; }
            kc++;
        }
        __syncthreads();
    }

    float4* out4 = (float4*)outp + (size_t)b * PC;
    for (int r = tid; r < PC; r += 256) {
        float4 v;
        if (r < kc) v = keptBox[r];
        else { v.x = 0.0f; v.y = 0.0f; v.z = 0.0f; v.w = 0.0f; }
        out4[r] = v;
    }
}

extern "C" void kernel_launch(void* const* d_in, const int* in_sizes, int n_in,
                              void* d_out, int out_size, void* d_ws, size_t ws_size,
                              hipStream_t stream) {
    const float* probs   = (const float*)d_in[0];
    const float* deltas  = (const float*)d_in[1];
    const float* anchors = (const float*)d_in[2];
    float* outp = (float*)d_out;

    u32* ws32 = (u32*)d_ws;
    u32* hist1 = ws32 + HIST1_OFF;
    u32* hist2 = ws32 + HIST2_OFF;
    u32* sel   = ws32 + SEL_OFF;
    u32* candCount = ws32 + CNT_OFF;
    u64* cand   = (u64*)(ws32 + ZERO_WORDS);
    u64* sorted = cand + (size_t)BB * CAP;
    float* boxesF = (float*)(sorted + (size_t)BB * KSEL);
    float4* boxes = (float4*)boxesF;
    u64* mask = (u64*)(boxesF + (size_t)BB * KSEL * 4);

    size_t needed = (size_t)ZERO_WORDS * 4 + (size_t)BB * CAP * 8 + (size_t)BB * KSEL * 8
                  + (size_t)BB * KSEL * 16 + (size_t)BB * NR * NWP * 8;

    hipLaunchKernelGGL(k_zero, dim3((ZERO_WORDS + 255) / 256), dim3(256), 0, stream, ws32);
    hipLaunchKernelGGL(k_hist1, dim3(HB, BB), dim3(256), 0, stream, (const float2*)probs, hist1);
    hipLaunchKernelGGL(k_sel1, dim3(BB), dim3(256), 0, stream, hist1, sel);
    hipLaunchKernelGGL(k_hist2, dim3(HB, BB), dim3(256), 0, stream, (const float2*)probs, sel, hist2);
    hipLaunchKernelGGL(k_sel2, dim3(BB), dim3(256), 0, stream, hist2, sel);
    hipLaunchKernelGGL(k_compact, dim3(CB, BB), dim3(256), 0, stream, (const float2*)probs, sel, candCount, cand);
    if (ws_size >= needed) {
        hipLaunchKernelGGL(k_rank, dim3(CAP / 512, BB), dim3(512), 0, stream, cand, candCount, sorted);
        hipLaunchKernelGGL(k_decode, dim3((KSEL + 255) / 256, BB), dim3(256), 0, stream,
                           sorted, (const float4*)anchors, (const float4*)deltas, boxes);
        hipLaunchKernelGGL(k_iou, dim3(NW, COLSPLIT, BB), dim3(256), 0, stream, boxes, mask);
        hipLaunchKernelGGL(k_reduce, dim3(BB), dim3(64), 0, stream, mask, boxes, outp);
    } else {
        hipLaunchKernelGGL(k_sortgather, dim3(BB), dim3(1024), 0, stream,
                           cand, candCount, (const float4*)anchors, (const float4*)deltas, boxes);
        hipLaunchKernelGGL(k_nms, dim3(BB), dim3(256), 0, stream, boxes, outp);
    }
}

// Round 14
// 291.984 us; speedup vs baseline: 1.0256x; 1.0256x over previous
//
#include <hip/hip_runtime.h>

typedef unsigned int u32;
typedef unsigned long long u64;

#define BB 4
#define NN 261888
#define KSEL 6000
#define CAP 8192
#define PC 1000
#define NMS_THR 0.7f
#define NW 94          /* words used */
#define NWP 96         /* padded row stride in words (768B rows, 16B aligned) */
#define NR (NW*64)     /* padded mask rows = 6016 */
#define COLSPLIT 6

#define HB 31
#define CHUNK_H (NN/HB)
#define HITER (CHUNK_H/256)
#define CB 93
#define CHUNK_C (NN/CB)
#define CITER (CHUNK_C/256)

// ---------------- ws layout (u32 units) ----------------
#define HIST1_OFF 0
#define HIST2_OFF (BB*2048)
#define SEL_OFF   (BB*2048*2)
#define CNT_OFF   (BB*2048*2 + BB*4)
#define ZERO_WORDS (BB*2048*2 + BB*4 + BB*32)

__global__ void k_zero(u32* ws) {
    int i = blockIdx.x * 256 + threadIdx.x;
    if (i < ZERO_WORDS) ws[i] = 0u;
}

__global__ void k_hist1(const float2* __restrict__ probs2, u32* __restrict__ hist1) {
    __shared__ u32 lh[2048];
    int b = blockIdx.y;
    size_t base = (size_t)b * NN + (size_t)blockIdx.x * CHUNK_H;
    for (int j = threadIdx.x; j < 2048; j += 256) lh[j] = 0u;
    __syncthreads();
    #pragma unroll 4
    for (int it = 0; it < HITER; ++it) {
        float2 p = probs2[base + it * 256 + threadIdx.x];
        atomicAdd(&lh[__float_as_uint(p.y) >> 21], 1u);
    }
    __syncthreads();
    for (int j = threadIdx.x; j < 2048; j += 256) {
        u32 c = lh[j];
        if (c) atomicAdd(&hist1[b * 2048 + j], c);
    }
}

__global__ void k_sel1(const u32* __restrict__ hist1, u32* __restrict__ sel) {
    __shared__ u32 gsum[256];
    __shared__ u32 lh[2048];
    int b = blockIdx.x;
    int t = threadIdx.x;
    u32 s = 0;
    #pragma unroll
    for (int j = 0; j < 8; ++j) {
        u32 v = hist1[b * 2048 + 2047 - (t * 8 + j)];
        lh[t * 8 + j] = v;
        s += v;
    }
    gsum[t] = s;
    __syncthreads();
    if (t == 0) {
        u32 cum = 0;
        for (int g = 0; g < 256; ++g) {
            if (cum + gsum[g] >= (u32)KSEL) {
                for (int j = 0; j < 8; ++j) {
                    u32 c = lh[g * 8 + j];
                    if (cum + c >= (u32)KSEL) {
                        sel[b * 4 + 0] = (u32)(2047 - (g * 8 + j));
                        sel[b * 4 + 1] = cum;
                        break;
                    }
                    cum += c;
                }
                break;
            }
            cum += gsum[g];
        }
    }
}

__global__ void k_hist2(const float2* __restrict__ probs2, const u32* __restrict__ sel,
                        u32* __restrict__ hist2) {
    int b = blockIdx.y;
    u32 b1 = sel[b * 4 + 0];
    size_t base = (size_t)b * NN + (size_t)blockIdx.x * CHUNK_H;
    #pragma unroll 4
    for (int it = 0; it < HITER; ++it) {
        float2 p = probs2[base + it * 256 + threadIdx.x];
        u32 key = __float_as_uint(p.y);
        if ((key >> 21) == b1) atomicAdd(&hist2[b * 2048 + ((key >> 10) & 2047u)], 1u);
    }
}

__global__ void k_sel2(const u32* __restrict__ hist2, u32* __restrict__ sel) {
    __shared__ u32 gsum[256];
    __shared__ u32 lh[2048];
    int b = blockIdx.x;
    int t = threadIdx.x;
    u32 s = 0;
    #pragma unroll
    for (int j = 0; j < 8; ++j) {
        u32 v = hist2[b * 2048 + 2047 - (t * 8 + j)];
        lh[t * 8 + j] = v;
        s += v;
    }
    gsum[t] = s;
    __syncthreads();
    if (t == 0) {
        u32 cum = sel[b * 4 + 1];
        u32 b1 = sel[b * 4 + 0];
        for (int g = 0; g < 256; ++g) {
            if (cum + gsum[g] >= (u32)KSEL) {
                for (int j = 0; j < 8; ++j) {
                    cum += lh[g * 8 + j];
                    if (cum >= (u32)KSEL) {
                        sel[b * 4 + 2] = (b1 << 11) | (u32)(2047 - (g * 8 + j));
                        break;
                    }
                }
                break;
            }
            cum += gsum[g];
        }
    }
}

__global__ void k_compact(const float2* __restrict__ probs2, const u32* __restrict__ sel,
                          u32* __restrict__ candCount, u64* __restrict__ cand) {
    __shared__ u32 wsum[4];
    __shared__ u32 blkBase;
    int b = blockIdx.y;
    int tid = threadIdx.x;
    int wave = tid >> 6, lane = tid & 63;
    u32 base = (u32)blockIdx.x * CHUNK_C;
    u32 thr = sel[b * 4 + 2];

    u32 keys[CITER];
    u32 cnt = 0;
    #pragma unroll
    for (int it = 0; it < CITER; ++it) {
        float2 p = probs2[(size_t)b * NN + base + it * 256 + tid];
        u32 key = __float_as_uint(p.y);
        keys[it] = key;
        cnt += ((key >> 10) >= thr) ? 1u : 0u;
    }
    #pragma unroll
    for (int off = 32; off; off >>= 1) cnt += __shfl_down(cnt, off);
    if (lane == 0) wsum[wave] = cnt;
    __syncthreads();
    if (tid == 0) {
        u32 w0 = wsum[0], w1 = wsum[1], w2 = wsum[2], w3 = wsum[3];
        u32 tot = w0 + w1 + w2 + w3;
        wsum[0] = 0; wsum[1] = w0; wsum[2] = w0 + w1; wsum[3] = w0 + w1 + w2;
        blkBase = tot ? atomicAdd(&candCount[b * 32], tot) : 0u;
    }
    __syncthreads();
    u32 run = blkBase + wsum[wave];
    u64* cb = cand + (size_t)b * CAP;
    #pragma unroll
    for (int it = 0; it < CITER; ++it) {
        u32 key = keys[it];
        bool pred = (key >> 10) >= thr;
        u64 m = __ballot(pred);
        if (pred) {
            u32 pos = run + (u32)__popcll(m & ((1ull << lane) - 1ull));
            u32 gi = base + it * 256 + tid;
            if (pos < CAP) cb[pos] = ((u64)key << 32) | (u32)(~gi);
        }
        run += (u32)__popcll(m);
    }
}

__global__ __launch_bounds__(512) void k_rank(const u64* __restrict__ cand,
                                              const u32* __restrict__ candCount,
                                              u64* __restrict__ sorted) {
    __shared__ u64 keys[CAP];
    int b = blockIdx.y;
    int tid = threadIdx.x;
    int cnt = (int)candCount[b * 32];
    if (cnt > CAP) cnt = CAP;
    const u64* cb = cand + (size_t)b * CAP;
    for (int j = tid; j < CAP; j += 512)
        keys[j] = (j < cnt) ? cb[j] : 0ull;
    __syncthreads();
    int r = blockIdx.x * 512 + tid;
    if (r >= cnt) return;
    u64 my = keys[r];
    int cnt16 = (cnt + 15) & ~15;
    int rank = 0;
    for (int j = 0; j < cnt16; j += 16) {
        #pragma unroll
        for (int u = 0; u < 16; ++u)
            rank += (keys[j + u] > my) ? 1 : 0;
    }
    if (rank < KSEL) sorted[(size_t)b * KSEL + rank] = my;
}

__global__ void k_decode(const u64* __restrict__ sorted,
                         const float4* __restrict__ anchors, const float4* __restrict__ deltas,
                         float4* __restrict__ boxes) {
    int b = blockIdx.y;
    int t = blockIdx.x * 256 + threadIdx.x;
    if (t >= KSEL) return;
    u64 sk = sorted[(size_t)b * KSEL + t];
    u32 idx = ~(u32)(sk & 0xFFFFFFFFull);
    if (idx >= NN) idx = NN - 1;
    float4 a = anchors[(size_t)b * NN + idx];
    float4 d = deltas[(size_t)b * NN + idx];
    float dy = __fmul_rn(d.x, 0.1f);
    float dx = __fmul_rn(d.y, 0.1f);
    float dh = __fmul_rn(d.z, 0.2f);
    float dw = __fmul_rn(d.w, 0.2f);
    float h  = __fsub_rn(a.z, a.x);
    float w  = __fsub_rn(a.w, a.y);
    float cy = __fadd_rn(__fadd_rn(a.x, __fmul_rn(0.5f, h)), __fmul_rn(dy, h));
    float cx = __fadd_rn(__fadd_rn(a.y, __fmul_rn(0.5f, w)), __fmul_rn(dx, w));
    float h2 = __fmul_rn(h, expf(dh));
    float w2 = __fmul_rn(w, expf(dw));
    float y1 = __fsub_rn(cy, __fmul_rn(0.5f, h2));
    float x1 = __fsub_rn(cx, __fmul_rn(0.5f, w2));
    float y2 = __fadd_rn(y1, h2);
    float x2 = __fadd_rn(x1, w2);
    y1 = fminf(fmaxf(y1, 0.0f), 1.0f);
    x1 = fminf(fmaxf(x1, 0.0f), 1.0f);
    y2 = fminf(fmaxf(y2, 0.0f), 1.0f);
    x2 = fminf(fmaxf(x2, 0.0f), 1.0f);
    float4 out;
    out.x = y1; out.y = x1; out.z = y2; out.w = x2;
    boxes[(size_t)b * KSEL + t] = out;
}

__global__ void k_sortgather(const u64* __restrict__ cand, const u32* __restrict__ candCount,
                             const float4* __restrict__ anchors, const float4* __restrict__ deltas,
                             float4* __restrict__ boxes) {
    __shared__ u64 s[CAP];
    int b = blockIdx.x;
    int tid = threadIdx.x;
    u32 cnt = candCount[b * 32];
    if (cnt > CAP) cnt = CAP;
    for (int j = tid; j < CAP; j += 1024)
        s[j] = (j < (int)cnt) ? cand[(size_t)b * CAP + j] : 0ull;
    __syncthreads();
    for (int k = 2; k <= CAP; k <<= 1) {
        for (int j = k >> 1; j > 0; j >>= 1) {
            for (int idx = tid; idx < CAP; idx += 1024) {
                int l = idx ^ j;
                if (l > idx) {
                    u64 a = s[idx], c = s[l];
                    bool dir = ((idx & k) == 0);
                    if ((a < c) == dir) { s[idx] = c; s[l] = a; }
                }
            }
            __syncthreads();
        }
    }
    for (int t = tid; t < KSEL; t += 1024) {
        u64 sk = s[t];
        u32 idx = ~(u32)(sk & 0xFFFFFFFFull);
        float4 a = anchors[(size_t)b * NN + idx];
        float4 d = deltas[(size_t)b * NN + idx];
        float dy = __fmul_rn(d.x, 0.1f);
        float dx = __fmul_rn(d.y, 0.1f);
        float dh = __fmul_rn(d.z, 0.2f);
        float dw = __fmul_rn(d.w, 0.2f);
        float h  = __fsub_rn(a.z, a.x);
        float w  = __fsub_rn(a.w, a.y);
        float cy = __fadd_rn(__fadd_rn(a.x, __fmul_rn(0.5f, h)), __fmul_rn(dy, h));
        float cx = __fadd_rn(__fadd_rn(a.y, __fmul_rn(0.5f, w)), __fmul_rn(dx, w));
        float h2 = __fmul_rn(h, expf(dh));
        float w2 = __fmul_rn(w, expf(dw));
        float y1 = __fsub_rn(cy, __fmul_rn(0.5f, h2));
        float x1 = __fsub_rn(cx, __fmul_rn(0.5f, w2));
        float y2 = __fadd_rn(y1, h2);
        float x2 = __fadd_rn(x1, w2);
        y1 = fminf(fmaxf(y1, 0.0f), 1.0f);
        x1 = fminf(fmaxf(x1, 0.0f), 1.0f);
        y2 = fminf(fmaxf(y2, 0.0f), 1.0f);
        x2 = fminf(fmaxf(x2, 0.0f), 1.0f);
        float4 out;
        out.x = y1; out.y = x1; out.z = y2; out.w = x2;
        boxes[(size_t)b * KSEL + t] = out;
    }
}

// ---------- phase 1: upper-triangle bitmask, row-major, stride NWP ----------
__global__ __launch_bounds__(256) void k_iou(const float4* __restrict__ boxes,
                                             u64* __restrict__ mask) {
    __shared__ float4 colBox[4][64];
    __shared__ float  colArea[4][64];
    int b = blockIdx.z;
    int rblk = blockIdx.x;
    int r0 = rblk * 64;
    int tid = threadIdx.x;
    int wave = tid >> 6, lane = tid & 63;
    const float4* B4 = boxes + (size_t)b * KSEL;

    int r = r0 + lane;
    float4 rb;
    if (r < KSEL) rb = B4[r];
    else { rb.x = 2.0f; rb.y = 2.0f; rb.z = 3.0f; rb.w = 3.0f; }
    float ra = __fmul_rn(__fsub_rn(rb.z, rb.x), __fsub_rn(rb.w, rb.y));

    const double M0 = 0.5 * ((double)__uint_as_float(0x3F333333u)
                           + (double)__uint_as_float(0x3F333334u));
    u64* Mb = mask + (size_t)b * NR * NWP;

    for (int jw = rblk + blockIdx.y * 4 + wave; jw < NW; jw += 4 * COLSPLIT) {
        int j = jw * 64 + lane;
        float4 cbx;
        if (j < KSEL) cbx = B4[j];
        else { cbx.x = 2.0f; cbx.y = 2.0f; cbx.z = 3.0f; cbx.w = 3.0f; }
        colBox[wave][lane] = cbx;
        colArea[wave][lane] = __fmul_rn(__fsub_rn(cbx.z, cbx.x), __fsub_rn(cbx.w, cbx.y));
        asm volatile("" ::: "memory");

        u64 word = 0ull;
        #pragma unroll
        for (int c = 0; c < 64; ++c) {
            float4 cb = colBox[wave][c];
            float ca = colArea[wave][c];
            float ih = fmaxf(__fsub_rn(fminf(rb.z, cb.z), fmaxf(rb.x, cb.x)), 0.0f);
            float iw = fmaxf(__fsub_rn(fminf(rb.w, cb.w), fmaxf(rb.y, cb.y)), 0.0f);
            float inter = __fmul_rn(ih, iw);
            float denom = __fadd_rn(__fsub_rn(__fadd_rn(ra, ca), inter), 1e-8f);
            bool pred = ((double)inter >= M0 * (double)denom);
            word |= ((u64)pred) << c;
        }
        Mb[(size_t)(r0 + lane) * NWP + jw] = word;
        asm volatile("" ::: "memory");
    }
}

// ---------- phase 2: 8-wave parallel reduce, defensive sync ----------
// Wave w owns rows g*64+w*8..+7. Lane l (clamped 46) holds words 2l (rwA),
// 2l+1 (rwB). DECIDE(g) redundant in all waves from rem = OR pub[0..7]
// (single buffer; read -> barrier -> write -> barrier). Publish value made
// wave-uniform via readlane64 BEFORE the lane-0 store.
__device__ __forceinline__ u64 readlane64(u64 v, int lane) {
    u32 lo = (u32)__builtin_amdgcn_readlane((int)(u32)v, lane);
    u32 hi = (u32)__builtin_amdgcn_readlane((int)(u32)(v >> 32), lane);
    return ((u64)hi << 32) | (u64)lo;
}

__global__ __launch_bounds__(512) void k_reduce(const u64* __restrict__ mask,
                                                const float4* __restrict__ boxes,
                                                float* __restrict__ outp) {
    __shared__ u64 pub[8];
    __shared__ u32 keptIdx[PC];
    int b = blockIdx.x;
    int tid = threadIdx.x;
    int wv = tid >> 6, lane = tid & 63;
    const u64* M = mask + (size_t)b * NR * NWP;
    const float4* B4 = boxes + (size_t)b * KSEL;
    int lp = lane < 46 ? lane : 46;     // words 2lp,2lp+1 <= 93: no pad reads
    u64 rwA = 0ull, rwB = 0ull;
    int k = 0, kprev = 0;

    if (tid < 8) pub[tid] = 0ull;

    ulonglong2 cur[8], nxt[8];
    u64 dgCur, dgNxt;
    #pragma unroll
    for (int r = 0; r < 8; ++r)
        cur[r] = *(const ulonglong2*)(M + (size_t)(wv * 8 + r) * NWP + 2 * lp);
    dgCur = M[(size_t)lane * NWP + 0];
    __syncthreads();   // pub init visible

    for (int g = 0; g < NW; ++g) {
        // prefetch next group (loads fly under DECIDE+ACCUM+barriers)
        int gn = (g + 1 < NW) ? g + 1 : g;
        #pragma unroll
        for (int r = 0; r < 8; ++r)
            nxt[r] = *(const ulonglong2*)(M + (size_t)(gn * 64 + wv * 8 + r) * NWP + 2 * lp);
        dgNxt = M[(size_t)(gn * 64 + lane) * NWP + gn];

        // DECIDE(g): rem = word g of removed mask over groups < g
        u64 rem = pub[0] | pub[1] | pub[2] | pub[3] | pub[4] | pub[5] | pub[6] | pub[7];
        int remaining = KSEL - g * 64;
        u64 valid = (remaining >= 64) ? ~0ull : ((1ull << remaining) - 1ull);
        u64 todo = ~rem & valid;
        u64 kb = 0ull;
        while (todo && k < PC) {
            int i = (int)__builtin_ctzll(todo);
            kb |= (1ull << i);
            ++k;
            u64 drow = readlane64(dgCur, i);
            todo &= ~(drow | (1ull << i));
        }
        if (wv == 0 && ((kb >> lane) & 1ull)) {
            int rank = kprev + (int)__popcll(kb & ((1ull << lane) - 1ull));
            keptIdx[rank] = (u32)(g * 64 + lane);
        }
        kprev = k;

        // ACCUM kept rows of group g into this wave's partials
        #pragma unroll
        for (int r = 0; r < 8; ++r)
            if ((kb >> (wv * 8 + r)) & 1ull) { rwA |= cur[r].x; rwB |= cur[r].y; }

        if (k >= PC || g == NW - 1) break;   // uniform (k identical in all waves)

        // publish word g+1 (wave-uniform value), two-barrier discipline
        int nw_ = g + 1;
        u64 wpub = (nw_ & 1) ? readlane64(rwB, nw_ >> 1) : readlane64(rwA, nw_ >> 1);
        __syncthreads();                 // all waves done reading pub for group g
        if (lane == 0) pub[wv] = wpub;
        __syncthreads();                 // publish visible for group g+1

        #pragma unroll
        for (int r = 0; r < 8; ++r) cur[r] = nxt[r];
        dgCur = dgNxt;
    }
    __syncthreads();   // keptIdx visible to all threads

    float4* O = (float4*)outp + (size_t)b * PC;
    for (int t = tid; t < PC; t += 512) {
        float4 v; v.x = 0.0f; v.y = 0.0f; v.z = 0.0f; v.w = 0.0f;
        if (t < k) v = B4[keptIdx[t]];
        O[t] = v;
    }
}

// ---------- fallback serial NMS (used only if ws too small for mask) ----------
__global__ void k_nms(const float4* __restrict__ boxes, float* __restrict__ outp) {
    __shared__ float4 chunk[512];
    __shared__ float4 keptBox[PC];
    __shared__ float  keptArea[PC];
    __shared__ u32    flag[2];
    int b = blockIdx.x;
    int tid = threadIdx.x;
    const float4* B4 = boxes + (size_t)b * KSEL;

    if (tid < 2) flag[tid] = 0u;
    for (int j = tid; j < 512; j += 256) chunk[j] = B4[j];
    __syncthreads();

    int kc = 0;
    for (int i = 0; i < KSEL && kc < PC; ++i) {
        int ci = i & 511;
        if (ci == 0 && i != 0) {
            for (int j = tid; j < 512 && (i + j) < KSEL; j += 256) chunk[j] = B4[i + j];
            __syncthreads();
        }
        float4 cb = chunk[ci];
        float careaV = __fmul_rn(__fsub_rn(cb.z, cb.x), __fsub_rn(cb.w, cb.y));
        bool sup = false;
        for (int t = tid; t < kc; t += 256) {
            float4 kb2 = keptBox[t];
            float ih = fmaxf(__fsub_rn(fminf(cb.z, kb2.z), fmaxf(cb.x, kb2.x)), 0.0f);
            float iw = fmaxf(__fsub_rn(fminf(cb.w, kb2.w), fmaxf(cb.y, kb2.y)), 0.0f);
            float inter = __fmul_rn(ih, iw);
            float denom = __fadd_rn(__fsub_rn(__fadd_rn(careaV, keptArea[t]), inter), 1e-8f);
            if (__fdiv_rn(inter, denom) > NMS_THR) sup = true;
        }
        int p = i & 1;
        if (sup) flag[p] = 1u;
        if (tid == 0) flag[p ^ 1] = 0u;
        __syncthreads();
        if (flag[p] == 0u) {
            if (tid == 0) { keptBox[kc] = cb; keptArea[kc] = careaV; }
            kc++;
        }
        __syncthreads();
    }

    float4* out4 = (float4*)outp + (size_t)b * PC;
    for (int r = tid; r < PC; r += 256) {
        float4 v;
        if (r < kc) v = keptBox[r];
        else { v.x = 0.0f; v.y = 0.0f; v.z = 0.0f; v.w = 0.0f; }
        out4[r] = v;
    }
}

extern "C" void kernel_launch(void* const* d_in, const int* in_sizes, int n_in,
                              void* d_out, int out_size, void* d_ws, size_t ws_size,
                              hipStream_t stream) {
    const float* probs   = (const float*)d_in[0];
    const float* deltas  = (const float*)d_in[1];
    const float* anchors = (const float*)d_in[2];
    float* outp = (float*)d_out;

    u32* ws32 = (u32*)d_ws;
    u32* hist1 = ws32 + HIST1_OFF;
    u32* hist2 = ws32 + HIST2_OFF;
    u32* sel   = ws32 + SEL_OFF;
    u32* candCount = ws32 + CNT_OFF;
    u64* cand   = (u64*)(ws32 + ZERO_WORDS);
    u64* sorted = cand + (size_t)BB * CAP;
    float* boxesF = (float*)(sorted + (size_t)BB * KSEL);
    float4* boxes = (float4*)boxesF;
    u64* mask = (u64*)(boxesF + (size_t)BB * KSEL * 4);

    size_t needed = (size_t)ZERO_WORDS * 4 + (size_t)BB * CAP * 8 + (size_t)BB * KSEL * 8
                  + (size_t)BB * KSEL * 16 + (size_t)BB * NR * NWP * 8;

    hipLaunchKernelGGL(k_zero, dim3((ZERO_WORDS + 255) / 256), dim3(256), 0, stream, ws32);
    hipLaunchKernelGGL(k_hist1, dim3(HB, BB), dim3(256), 0, stream, (const float2*)probs, hist1);
    hipLaunchKernelGGL(k_sel1, dim3(BB), dim3(256), 0, stream, hist1, sel);
    hipLaunchKernelGGL(k_hist2, dim3(HB, BB), dim3(256), 0, stream, (const float2*)probs, sel, hist2);
    hipLaunchKernelGGL(k_sel2, dim3(BB), dim3(256), 0, stream, hist2, sel);
    hipLaunchKernelGGL(k_compact, dim3(CB, BB), dim3(256), 0, stream, (const float2*)probs, sel, candCount, cand);
    if (ws_size >= needed) {
        hipLaunchKernelGGL(k_rank, dim3(CAP / 512, BB), dim3(512), 0, stream, cand, candCount, sorted);
        hipLaunchKernelGGL(k_decode, dim3((KSEL + 255) / 256, BB), dim3(256), 0, stream,
                           sorted, (const float4*)anchors, (const float4*)deltas, boxes);
        hipLaunchKernelGGL(k_iou, dim3(NW, COLSPLIT, BB), dim3(256), 0, stream, boxes, mask);
        hipLaunchKernelGGL(k_reduce, dim3(BB), dim3(512), 0, stream, mask, boxes, outp);
    } else {
        hipLaunchKernelGGL(k_sortgather, dim3(BB), dim3(1024), 0, stream,
                           cand, candCount, (const float4*)anchors, (const float4*)deltas, boxes);
        hipLaunchKernelGGL(k_nms, dim3(BB), dim3(256), 0, stream, boxes, outp);
    }
}

// Round 15
// 275.312 us; speedup vs baseline: 1.0877x; 1.0606x over previous
//
#include <hip/hip_runtime.h>

typedef unsigned int u32;
typedef unsigned long long u64;

#define BB 4
#define NN 261888
#define KSEL 6000
#define CAP 8192
#define PC 1000
#define NMS_THR 0.7f
#define NW 94          /* words used */
#define NWP 96         /* padded row stride in words (768B rows, 16B aligned) */
#define NR (NW*64)     /* padded mask rows = 6016 */
#define COLSPLIT 6

#define HB 31
#define CHUNK_H (NN/HB)
#define HITER (CHUNK_H/256)
#define CB 93
#define CHUNK_C (NN/CB)
#define CITER (CHUNK_C/256)

// ---------------- ws layout (u32 units) ----------------
#define HIST1_OFF 0
#define HIST2_OFF (BB*2048)
#define SEL_OFF   (BB*2048*2)
#define CNT_OFF   (BB*2048*2 + BB*4)
#define ZERO_WORDS (BB*2048*2 + BB*4 + BB*32)

__global__ void k_zero(u32* ws) {
    int i = blockIdx.x * 256 + threadIdx.x;
    if (i < ZERO_WORDS) ws[i] = 0u;
}

__global__ void k_hist1(const float2* __restrict__ probs2, u32* __restrict__ hist1) {
    __shared__ u32 lh[2048];
    int b = blockIdx.y;
    size_t base = (size_t)b * NN + (size_t)blockIdx.x * CHUNK_H;
    for (int j = threadIdx.x; j < 2048; j += 256) lh[j] = 0u;
    __syncthreads();
    #pragma unroll 4
    for (int it = 0; it < HITER; ++it) {
        float2 p = probs2[base + it * 256 + threadIdx.x];
        atomicAdd(&lh[__float_as_uint(p.y) >> 21], 1u);
    }
    __syncthreads();
    for (int j = threadIdx.x; j < 2048; j += 256) {
        u32 c = lh[j];
        if (c) atomicAdd(&hist1[b * 2048 + j], c);
    }
}

__global__ void k_sel1(const u32* __restrict__ hist1, u32* __restrict__ sel) {
    __shared__ u32 gsum[256];
    __shared__ u32 lh[2048];
    int b = blockIdx.x;
    int t = threadIdx.x;
    u32 s = 0;
    #pragma unroll
    for (int j = 0; j < 8; ++j) {
        u32 v = hist1[b * 2048 + 2047 - (t * 8 + j)];
        lh[t * 8 + j] = v;
        s += v;
    }
    gsum[t] = s;
    __syncthreads();
    if (t == 0) {
        u32 cum = 0;
        for (int g = 0; g < 256; ++g) {
            if (cum + gsum[g] >= (u32)KSEL) {
                for (int j = 0; j < 8; ++j) {
                    u32 c = lh[g * 8 + j];
                    if (cum + c >= (u32)KSEL) {
                        sel[b * 4 + 0] = (u32)(2047 - (g * 8 + j));
                        sel[b * 4 + 1] = cum;
                        break;
                    }
                    cum += c;
                }
                break;
            }
            cum += gsum[g];
        }
    }
}

__global__ void k_hist2(const float2* __restrict__ probs2, const u32* __restrict__ sel,
                        u32* __restrict__ hist2) {
    int b = blockIdx.y;
    u32 b1 = sel[b * 4 + 0];
    size_t base = (size_t)b * NN + (size_t)blockIdx.x * CHUNK_H;
    #pragma unroll 4
    for (int it = 0; it < HITER; ++it) {
        float2 p = probs2[base + it * 256 + threadIdx.x];
        u32 key = __float_as_uint(p.y);
        if ((key >> 21) == b1) atomicAdd(&hist2[b * 2048 + ((key >> 10) & 2047u)], 1u);
    }
}

__global__ void k_sel2(const u32* __restrict__ hist2, u32* __restrict__ sel) {
    __shared__ u32 gsum[256];
    __shared__ u32 lh[2048];
    int b = blockIdx.x;
    int t = threadIdx.x;
    u32 s = 0;
    #pragma unroll
    for (int j = 0; j < 8; ++j) {
        u32 v = hist2[b * 2048 + 2047 - (t * 8 + j)];
        lh[t * 8 + j] = v;
        s += v;
    }
    gsum[t] = s;
    __syncthreads();
    if (t == 0) {
        u32 cum = sel[b * 4 + 1];
        u32 b1 = sel[b * 4 + 0];
        for (int g = 0; g < 256; ++g) {
            if (cum + gsum[g] >= (u32)KSEL) {
                for (int j = 0; j < 8; ++j) {
                    cum += lh[g * 8 + j];
                    if (cum >= (u32)KSEL) {
                        sel[b * 4 + 2] = (b1 << 11) | (u32)(2047 - (g * 8 + j));
                        break;
                    }
                }
                break;
            }
            cum += gsum[g];
        }
    }
}

__global__ void k_compact(const float2* __restrict__ probs2, const u32* __restrict__ sel,
                          u32* __restrict__ candCount, u64* __restrict__ cand) {
    __shared__ u32 wsum[4];
    __shared__ u32 blkBase;
    int b = blockIdx.y;
    int tid = threadIdx.x;
    int wave = tid >> 6, lane = tid & 63;
    u32 base = (u32)blockIdx.x * CHUNK_C;
    u32 thr = sel[b * 4 + 2];

    u32 keys[CITER];
    u32 cnt = 0;
    #pragma unroll
    for (int it = 0; it < CITER; ++it) {
        float2 p = probs2[(size_t)b * NN + base + it * 256 + tid];
        u32 key = __float_as_uint(p.y);
        keys[it] = key;
        cnt += ((key >> 10) >= thr) ? 1u : 0u;
    }
    #pragma unroll
    for (int off = 32; off; off >>= 1) cnt += __shfl_down(cnt, off);
    if (lane == 0) wsum[wave] = cnt;
    __syncthreads();
    if (tid == 0) {
        u32 w0 = wsum[0], w1 = wsum[1], w2 = wsum[2], w3 = wsum[3];
        u32 tot = w0 + w1 + w2 + w3;
        wsum[0] = 0; wsum[1] = w0; wsum[2] = w0 + w1; wsum[3] = w0 + w1 + w2;
        blkBase = tot ? atomicAdd(&candCount[b * 32], tot) : 0u;
    }
    __syncthreads();
    u32 run = blkBase + wsum[wave];
    u64* cb = cand + (size_t)b * CAP;
    #pragma unroll
    for (int it = 0; it < CITER; ++it) {
        u32 key = keys[it];
        bool pred = (key >> 10) >= thr;
        u64 m = __ballot(pred);
        if (pred) {
            u32 pos = run + (u32)__popcll(m & ((1ull << lane) - 1ull));
            u32 gi = base + it * 256 + tid;
            if (pos < CAP) cb[pos] = ((u64)key << 32) | (u32)(~gi);
        }
        run += (u32)__popcll(m);
    }
}

__global__ __launch_bounds__(512) void k_rank(const u64* __restrict__ cand,
                                              const u32* __restrict__ candCount,
                                              u64* __restrict__ sorted) {
    __shared__ u64 keys[CAP];
    int b = blockIdx.y;
    int tid = threadIdx.x;
    int cnt = (int)candCount[b * 32];
    if (cnt > CAP) cnt = CAP;
    const u64* cb = cand + (size_t)b * CAP;
    for (int j = tid; j < CAP; j += 512)
        keys[j] = (j < cnt) ? cb[j] : 0ull;
    __syncthreads();
    int r = blockIdx.x * 512 + tid;
    if (r >= cnt) return;
    u64 my = keys[r];
    int cnt16 = (cnt + 15) & ~15;
    int rank = 0;
    for (int j = 0; j < cnt16; j += 16) {
        #pragma unroll
        for (int u = 0; u < 16; ++u)
            rank += (keys[j + u] > my) ? 1 : 0;
    }
    if (rank < KSEL) sorted[(size_t)b * KSEL + rank] = my;
}

__global__ void k_decode(const u64* __restrict__ sorted,
                         const float4* __restrict__ anchors, const float4* __restrict__ deltas,
                         float4* __restrict__ boxes) {
    int b = blockIdx.y;
    int t = blockIdx.x * 256 + threadIdx.x;
    if (t >= KSEL) return;
    u64 sk = sorted[(size_t)b * KSEL + t];
    u32 idx = ~(u32)(sk & 0xFFFFFFFFull);
    if (idx >= NN) idx = NN - 1;
    float4 a = anchors[(size_t)b * NN + idx];
    float4 d = deltas[(size_t)b * NN + idx];
    float dy = __fmul_rn(d.x, 0.1f);
    float dx = __fmul_rn(d.y, 0.1f);
    float dh = __fmul_rn(d.z, 0.2f);
    float dw = __fmul_rn(d.w, 0.2f);
    float h  = __fsub_rn(a.z, a.x);
    float w  = __fsub_rn(a.w, a.y);
    float cy = __fadd_rn(__fadd_rn(a.x, __fmul_rn(0.5f, h)), __fmul_rn(dy, h));
    float cx = __fadd_rn(__fadd_rn(a.y, __fmul_rn(0.5f, w)), __fmul_rn(dx, w));
    float h2 = __fmul_rn(h, expf(dh));
    float w2 = __fmul_rn(w, expf(dw));
    float y1 = __fsub_rn(cy, __fmul_rn(0.5f, h2));
    float x1 = __fsub_rn(cx, __fmul_rn(0.5f, w2));
    float y2 = __fadd_rn(y1, h2);
    float x2 = __fadd_rn(x1, w2);
    y1 = fminf(fmaxf(y1, 0.0f), 1.0f);
    x1 = fminf(fmaxf(x1, 0.0f), 1.0f);
    y2 = fminf(fmaxf(y2, 0.0f), 1.0f);
    x2 = fminf(fmaxf(x2, 0.0f), 1.0f);
    float4 out;
    out.x = y1; out.y = x1; out.z = y2; out.w = x2;
    boxes[(size_t)b * KSEL + t] = out;
}

__global__ void k_sortgather(const u64* __restrict__ cand, const u32* __restrict__ candCount,
                             const float4* __restrict__ anchors, const float4* __restrict__ deltas,
                             float4* __restrict__ boxes) {
    __shared__ u64 s[CAP];
    int b = blockIdx.x;
    int tid = threadIdx.x;
    u32 cnt = candCount[b * 32];
    if (cnt > CAP) cnt = CAP;
    for (int j = tid; j < CAP; j += 1024)
        s[j] = (j < (int)cnt) ? cand[(size_t)b * CAP + j] : 0ull;
    __syncthreads();
    for (int k = 2; k <= CAP; k <<= 1) {
        for (int j = k >> 1; j > 0; j >>= 1) {
            for (int idx = tid; idx < CAP; idx += 1024) {
                int l = idx ^ j;
                if (l > idx) {
                    u64 a = s[idx], c = s[l];
                    bool dir = ((idx & k) == 0);
                    if ((a < c) == dir) { s[idx] = c; s[l] = a; }
                }
            }
            __syncthreads();
        }
    }
    for (int t = tid; t < KSEL; t += 1024) {
        u64 sk = s[t];
        u32 idx = ~(u32)(sk & 0xFFFFFFFFull);
        float4 a = anchors[(size_t)b * NN + idx];
        float4 d = deltas[(size_t)b * NN + idx];
        float dy = __fmul_rn(d.x, 0.1f);
        float dx = __fmul_rn(d.y, 0.1f);
        float dh = __fmul_rn(d.z, 0.2f);
        float dw = __fmul_rn(d.w, 0.2f);
        float h  = __fsub_rn(a.z, a.x);
        float w  = __fsub_rn(a.w, a.y);
        float cy = __fadd_rn(__fadd_rn(a.x, __fmul_rn(0.5f, h)), __fmul_rn(dy, h));
        float cx = __fadd_rn(__fadd_rn(a.y, __fmul_rn(0.5f, w)), __fmul_rn(dx, w));
        float h2 = __fmul_rn(h, expf(dh));
        float w2 = __fmul_rn(w, expf(dw));
        float y1 = __fsub_rn(cy, __fmul_rn(0.5f, h2));
        float x1 = __fsub_rn(cx, __fmul_rn(0.5f, w2));
        float y2 = __fadd_rn(y1, h2);
        float x2 = __fadd_rn(x1, w2);
        y1 = fminf(fmaxf(y1, 0.0f), 1.0f);
        x1 = fminf(fmaxf(x1, 0.0f), 1.0f);
        y2 = fminf(fmaxf(y2, 0.0f), 1.0f);
        x2 = fminf(fmaxf(x2, 0.0f), 1.0f);
        float4 out;
        out.x = y1; out.y = x1; out.z = y2; out.w = x2;
        boxes[(size_t)b * KSEL + t] = out;
    }
}

// ---------- phase 1: upper-triangle bitmask, row-major, stride NWP ----------
__global__ __launch_bounds__(256) void k_iou(const float4* __restrict__ boxes,
                                             u64* __restrict__ mask) {
    __shared__ float4 colBox[4][64];
    __shared__ float  colArea[4][64];
    int b = blockIdx.z;
    int rblk = blockIdx.x;
    int r0 = rblk * 64;
    int tid = threadIdx.x;
    int wave = tid >> 6, lane = tid & 63;
    const float4* B4 = boxes + (size_t)b * KSEL;

    int r = r0 + lane;
    float4 rb;
    if (r < KSEL) rb = B4[r];
    else { rb.x = 2.0f; rb.y = 2.0f; rb.z = 3.0f; rb.w = 3.0f; }
    float ra = __fmul_rn(__fsub_rn(rb.z, rb.x), __fsub_rn(rb.w, rb.y));

    const double M0 = 0.5 * ((double)__uint_as_float(0x3F333333u)
                           + (double)__uint_as_float(0x3F333334u));
    u64* Mb = mask + (size_t)b * NR * NWP;

    for (int jw = rblk + blockIdx.y * 4 + wave; jw < NW; jw += 4 * COLSPLIT) {
        int j = jw * 64 + lane;
        float4 cbx;
        if (j < KSEL) cbx = B4[j];
        else { cbx.x = 2.0f; cbx.y = 2.0f; cbx.z = 3.0f; cbx.w = 3.0f; }
        colBox[wave][lane] = cbx;
        colArea[wave][lane] = __fmul_rn(__fsub_rn(cbx.z, cbx.x), __fsub_rn(cbx.w, cbx.y));
        asm volatile("" ::: "memory");

        u64 word = 0ull;
        #pragma unroll
        for (int c = 0; c < 64; ++c) {
            float4 cb = colBox[wave][c];
            float ca = colArea[wave][c];
            float ih = fmaxf(__fsub_rn(fminf(rb.z, cb.z), fmaxf(rb.x, cb.x)), 0.0f);
            float iw = fmaxf(__fsub_rn(fminf(rb.w, cb.w), fmaxf(rb.y, cb.y)), 0.0f);
            float inter = __fmul_rn(ih, iw);
            float denom = __fadd_rn(__fsub_rn(__fadd_rn(ra, ca), inter), 1e-8f);
            bool pred = ((double)inter >= M0 * (double)denom);
            word |= ((u64)pred) << c;
        }
        Mb[(size_t)(r0 + lane) * NWP + jw] = word;
        asm volatile("" ::: "memory");
    }
}

// ---------- phase 2: 8-wave parallel reduce, ballot-based DECIDE ----------
// Same structure as R13 (passing) with two changes:
// (1) row i's diag word via __ballot((dg>>i)&1) — IoU pred is exactly
//     symmetric, so lane c's dg bit i == row i's bit c. Kills the dynamic-
//     index readlane waterfall (~100cy -> ~5cy per kept row).
// (2) prefetch distance 2 (3-buffer rotate) to cover load latency.
__device__ __forceinline__ u64 readlane64(u64 v, int lane) {
    u32 lo = (u32)__builtin_amdgcn_readlane((int)(u32)v, lane);
    u32 hi = (u32)__builtin_amdgcn_readlane((int)(u32)(v >> 32), lane);
    return ((u64)hi << 32) | (u64)lo;
}

__global__ __launch_bounds__(512) void k_reduce(const u64* __restrict__ mask,
                                                const float4* __restrict__ boxes,
                                                float* __restrict__ outp) {
    __shared__ u64 pub[8];
    __shared__ u32 keptIdx[PC];
    int b = blockIdx.x;
    int tid = threadIdx.x;
    int wv = tid >> 6, lane = tid & 63;
    const u64* M = mask + (size_t)b * NR * NWP;
    const float4* B4 = boxes + (size_t)b * KSEL;
    int lp = lane < 46 ? lane : 46;     // words 2lp,2lp+1 <= 93: no pad reads
    u64 rwA = 0ull, rwB = 0ull;
    int k = 0, kprev = 0;

    if (tid < 8) pub[tid] = 0ull;

    ulonglong2 cur[8], mid[8], nxt[8];
    u64 dgCur, dgMid, dgNxt;
    #pragma unroll
    for (int r = 0; r < 8; ++r) {
        cur[r] = *(const ulonglong2*)(M + (size_t)(wv * 8 + r) * NWP + 2 * lp);
        mid[r] = *(const ulonglong2*)(M + (size_t)(64 + wv * 8 + r) * NWP + 2 * lp);
    }
    dgCur = M[(size_t)lane * NWP + 0];
    dgMid = M[(size_t)(64 + lane) * NWP + 1];
    __syncthreads();   // pub init visible

    for (int g = 0; g < NW; ++g) {
        // prefetch group g+2 (covered by ~2 groups of DECIDE+barriers)
        int gn = (g + 2 < NW) ? g + 2 : NW - 1;
        #pragma unroll
        for (int r = 0; r < 8; ++r)
            nxt[r] = *(const ulonglong2*)(M + (size_t)(gn * 64 + wv * 8 + r) * NWP + 2 * lp);
        dgNxt = M[(size_t)(gn * 64 + lane) * NWP + gn];

        // DECIDE(g): rem = word g of removed mask over groups < g
        u64 rem = pub[0] | pub[1] | pub[2] | pub[3] | pub[4] | pub[5] | pub[6] | pub[7];
        int remaining = KSEL - g * 64;
        u64 valid = (remaining >= 64) ? ~0ull : ((1ull << remaining) - 1ull);
        u64 todo = ~rem & valid;
        u64 kb = 0ull;
        while (todo && k < PC) {
            int i = (int)__builtin_ctzll(todo);    // uniform across lanes
            kb |= (1ull << i);
            ++k;
            u64 drow = __ballot((dgCur >> i) & 1ull);   // row i's word via symmetry
            todo &= ~(drow | (1ull << i));
        }
        if (wv == 0 && ((kb >> lane) & 1ull)) {
            int rank = kprev + (int)__popcll(kb & ((1ull << lane) - 1ull));
            keptIdx[rank] = (u32)(g * 64 + lane);
        }
        kprev = k;

        // ACCUM kept rows of group g into this wave's partials
        #pragma unroll
        for (int r = 0; r < 8; ++r)
            if ((kb >> (wv * 8 + r)) & 1ull) { rwA |= cur[r].x; rwB |= cur[r].y; }

        if (k >= PC || g == NW - 1) break;   // uniform (k identical in all waves)

        // publish word g+1 (wave-uniform value), two-barrier discipline
        int nw_ = g + 1;
        u64 wpub = (nw_ & 1) ? readlane64(rwB, nw_ >> 1) : readlane64(rwA, nw_ >> 1);
        __syncthreads();                 // all waves done reading pub for group g
        if (lane == 0) pub[wv] = wpub;
        __syncthreads();                 // publish visible for group g+1

        #pragma unroll
        for (int r = 0; r < 8; ++r) { cur[r] = mid[r]; mid[r] = nxt[r]; }
        dgCur = dgMid; dgMid = dgNxt;
    }
    __syncthreads();   // keptIdx visible to all threads

    float4* O = (float4*)outp + (size_t)b * PC;
    for (int t = tid; t < PC; t += 512) {
        float4 v; v.x = 0.0f; v.y = 0.0f; v.z = 0.0f; v.w = 0.0f;
        if (t < k) v = B4[keptIdx[t]];
        O[t] = v;
    }
}

// ---------- fallback serial NMS (used only if ws too small for mask) ----------
__global__ void k_nms(const float4* __restrict__ boxes, float* __restrict__ outp) {
    __shared__ float4 chunk[512];
    __shared__ float4 keptBox[PC];
    __shared__ float  keptArea[PC];
    __shared__ u32    flag[2];
    int b = blockIdx.x;
    int tid = threadIdx.x;
    const float4* B4 = boxes + (size_t)b * KSEL;

    if (tid < 2) flag[tid] = 0u;
    for (int j = tid; j < 512; j += 256) chunk[j] = B4[j];
    __syncthreads();

    int kc = 0;
    for (int i = 0; i < KSEL && kc < PC; ++i) {
        int ci = i & 511;
        if (ci == 0 && i != 0) {
            for (int j = tid; j < 512 && (i + j) < KSEL; j += 256) chunk[j] = B4[i + j];
            __syncthreads();
        }
        float4 cb = chunk[ci];
        float careaV = __fmul_rn(__fsub_rn(cb.z, cb.x), __fsub_rn(cb.w, cb.y));
        bool sup = false;
        for (int t = tid; t < kc; t += 256) {
            float4 kb2 = keptBox[t];
            float ih = fmaxf(__fsub_rn(fminf(cb.z, kb2.z), fmaxf(cb.x, kb2.x)), 0.0f);
            float iw = fmaxf(__fsub_rn(fminf(cb.w, kb2.w), fmaxf(cb.y, kb2.y)), 0.0f);
            float inter = __fmul_rn(ih, iw);
            float denom = __fadd_rn(__fsub_rn(__fadd_rn(careaV, keptArea[t]), inter), 1e-8f);
            if (__fdiv_rn(inter, denom) > NMS_THR) sup = true;
        }
        int p = i & 1;
        if (sup) flag[p] = 1u;
        if (tid == 0) flag[p ^ 1] = 0u;
        __syncthreads();
        if (flag[p] == 0u) {
            if (tid == 0) { keptBox[kc] = cb; keptArea[kc] = careaV; }
            kc++;
        }
        __syncthreads();
    }

    float4* out4 = (float4*)outp + (size_t)b * PC;
    for (int r = tid; r < PC; r += 256) {
        float4 v;
        if (r < kc) v = keptBox[r];
        else { v.x = 0.0f; v.y = 0.0f; v.z = 0.0f; v.w = 0.0f; }
        out4[r] = v;
    }
}

extern "C" void kernel_launch(void* const* d_in, const int* in_sizes, int n_in,
                              void* d_out, int out_size, void* d_ws, size_t ws_size,
                              hipStream_t stream) {
    const float* probs   = (const float*)d_in[0];
    const float* deltas  = (const float*)d_in[1];
    const float* anchors = (const float*)d_in[2];
    float* outp = (float*)d_out;

    u32* ws32 = (u32*)d_ws;
    u32* hist1 = ws32 + HIST1_OFF;
    u32* hist2 = ws32 + HIST2_OFF;
    u32* sel   = ws32 + SEL_OFF;
    u32* candCount = ws32 + CNT_OFF;
    u64* cand   = (u64*)(ws32 + ZERO_WORDS);
    u64* sorted = cand + (size_t)BB * CAP;
    float* boxesF = (float*)(sorted + (size_t)BB * KSEL);
    float4* boxes = (float4*)boxesF;
    u64* mask = (u64*)(boxesF + (size_t)BB * KSEL * 4);

    size_t needed = (size_t)ZERO_WORDS * 4 + (size_t)BB * CAP * 8 + (size_t)BB * KSEL * 8
                  + (size_t)BB * KSEL * 16 + (size_t)BB * NR * NWP * 8;

    hipLaunchKernelGGL(k_zero, dim3((ZERO_WORDS + 255) / 256), dim3(256), 0, stream, ws32);
    hipLaunchKernelGGL(k_hist1, dim3(HB, BB), dim3(256), 0, stream, (const float2*)probs, hist1);
    hipLaunchKernelGGL(k_sel1, dim3(BB), dim3(256), 0, stream, hist1, sel);
    hipLaunchKernelGGL(k_hist2, dim3(HB, BB), dim3(256), 0, stream, (const float2*)probs, sel, hist2);
    hipLaunchKernelGGL(k_sel2, dim3(BB), dim3(256), 0, stream, hist2, sel);
    hipLaunchKernelGGL(k_compact, dim3(CB, BB), dim3(256), 0, stream, (const float2*)probs, sel, candCount, cand);
    if (ws_size >= needed) {
        hipLaunchKernelGGL(k_rank, dim3(CAP / 512, BB), dim3(512), 0, stream, cand, candCount, sorted);
        hipLaunchKernelGGL(k_decode, dim3((KSEL + 255) / 256, BB), dim3(256), 0, stream,
                           sorted, (const float4*)anchors, (const float4*)deltas, boxes);
        hipLaunchKernelGGL(k_iou, dim3(NW, COLSPLIT, BB), dim3(256), 0, stream, boxes, mask);
        hipLaunchKernelGGL(k_reduce, dim3(BB), dim3(512), 0, stream, mask, boxes, outp);
    } else {
        hipLaunchKernelGGL(k_sortgather, dim3(BB), dim3(1024), 0, stream,
                           cand, candCount, (const float4*)anchors, (const float4*)deltas, boxes);
        hipLaunchKernelGGL(k_nms, dim3(BB), dim3(256), 0, stream, boxes, outp);
    }
}

// Round 16
// 260.982 us; speedup vs baseline: 1.1474x; 1.0549x over previous
//
#include <hip/hip_runtime.h>

typedef unsigned int u32;
typedef unsigned long long u64;

#define BB 4
#define NN 261888
#define KSEL 6000
#define CAP 8192
#define PC 1000
#define NMS_THR 0.7f
#define NW 94          /* words used */
#define NWP 96         /* padded row stride in words (768B rows, 16B aligned) */
#define NR (NW*64)     /* padded mask rows = 6016 */
#define COLSPLIT 6

#define HB 31
#define CHUNK_H (NN/HB)
#define HITER (CHUNK_H/256)
#define CB 93
#define CHUNK_C (NN/CB)
#define CITER (CHUNK_C/256)

// ---------------- ws layout (u32 units) ----------------
#define HIST1_OFF 0
#define HIST2_OFF (BB*2048)
#define SEL_OFF   (BB*2048*2)
#define CNT_OFF   (BB*2048*2 + BB*4)
#define ZERO_WORDS (BB*2048*2 + BB*4 + BB*32)

__global__ void k_zero(u32* ws) {
    int i = blockIdx.x * 256 + threadIdx.x;
    if (i < ZERO_WORDS) ws[i] = 0u;
}

__global__ void k_hist1(const float2* __restrict__ probs2, u32* __restrict__ hist1) {
    __shared__ u32 lh[2048];
    int b = blockIdx.y;
    size_t base = (size_t)b * NN + (size_t)blockIdx.x * CHUNK_H;
    for (int j = threadIdx.x; j < 2048; j += 256) lh[j] = 0u;
    __syncthreads();
    #pragma unroll 4
    for (int it = 0; it < HITER; ++it) {
        float2 p = probs2[base + it * 256 + threadIdx.x];
        atomicAdd(&lh[__float_as_uint(p.y) >> 21], 1u);
    }
    __syncthreads();
    for (int j = threadIdx.x; j < 2048; j += 256) {
        u32 c = lh[j];
        if (c) atomicAdd(&hist1[b * 2048 + j], c);
    }
}

__global__ void k_sel1(const u32* __restrict__ hist1, u32* __restrict__ sel) {
    __shared__ u32 gsum[256];
    __shared__ u32 lh[2048];
    int b = blockIdx.x;
    int t = threadIdx.x;
    u32 s = 0;
    #pragma unroll
    for (int j = 0; j < 8; ++j) {
        u32 v = hist1[b * 2048 + 2047 - (t * 8 + j)];
        lh[t * 8 + j] = v;
        s += v;
    }
    gsum[t] = s;
    __syncthreads();
    if (t == 0) {
        u32 cum = 0;
        for (int g = 0; g < 256; ++g) {
            if (cum + gsum[g] >= (u32)KSEL) {
                for (int j = 0; j < 8; ++j) {
                    u32 c = lh[g * 8 + j];
                    if (cum + c >= (u32)KSEL) {
                        sel[b * 4 + 0] = (u32)(2047 - (g * 8 + j));
                        sel[b * 4 + 1] = cum;
                        break;
                    }
                    cum += c;
                }
                break;
            }
            cum += gsum[g];
        }
    }
}

__global__ void k_hist2(const float2* __restrict__ probs2, const u32* __restrict__ sel,
                        u32* __restrict__ hist2) {
    int b = blockIdx.y;
    u32 b1 = sel[b * 4 + 0];
    size_t base = (size_t)b * NN + (size_t)blockIdx.x * CHUNK_H;
    #pragma unroll 4
    for (int it = 0; it < HITER; ++it) {
        float2 p = probs2[base + it * 256 + threadIdx.x];
        u32 key = __float_as_uint(p.y);
        if ((key >> 21) == b1) atomicAdd(&hist2[b * 2048 + ((key >> 10) & 2047u)], 1u);
    }
}

__global__ void k_sel2(const u32* __restrict__ hist2, u32* __restrict__ sel) {
    __shared__ u32 gsum[256];
    __shared__ u32 lh[2048];
    int b = blockIdx.x;
    int t = threadIdx.x;
    u32 s = 0;
    #pragma unroll
    for (int j = 0; j < 8; ++j) {
        u32 v = hist2[b * 2048 + 2047 - (t * 8 + j)];
        lh[t * 8 + j] = v;
        s += v;
    }
    gsum[t] = s;
    __syncthreads();
    if (t == 0) {
        u32 cum = sel[b * 4 + 1];
        u32 b1 = sel[b * 4 + 0];
        for (int g = 0; g < 256; ++g) {
            if (cum + gsum[g] >= (u32)KSEL) {
                for (int j = 0; j < 8; ++j) {
                    cum += lh[g * 8 + j];
                    if (cum >= (u32)KSEL) {
                        sel[b * 4 + 2] = (b1 << 11) | (u32)(2047 - (g * 8 + j));
                        break;
                    }
                }
                break;
            }
            cum += gsum[g];
        }
    }
}

__global__ void k_compact(const float2* __restrict__ probs2, const u32* __restrict__ sel,
                          u32* __restrict__ candCount, u64* __restrict__ cand) {
    __shared__ u32 wsum[4];
    __shared__ u32 blkBase;
    int b = blockIdx.y;
    int tid = threadIdx.x;
    int wave = tid >> 6, lane = tid & 63;
    u32 base = (u32)blockIdx.x * CHUNK_C;
    u32 thr = sel[b * 4 + 2];

    u32 keys[CITER];
    u32 cnt = 0;
    #pragma unroll
    for (int it = 0; it < CITER; ++it) {
        float2 p = probs2[(size_t)b * NN + base + it * 256 + tid];
        u32 key = __float_as_uint(p.y);
        keys[it] = key;
        cnt += ((key >> 10) >= thr) ? 1u : 0u;
    }
    #pragma unroll
    for (int off = 32; off; off >>= 1) cnt += __shfl_down(cnt, off);
    if (lane == 0) wsum[wave] = cnt;
    __syncthreads();
    if (tid == 0) {
        u32 w0 = wsum[0], w1 = wsum[1], w2 = wsum[2], w3 = wsum[3];
        u32 tot = w0 + w1 + w2 + w3;
        wsum[0] = 0; wsum[1] = w0; wsum[2] = w0 + w1; wsum[3] = w0 + w1 + w2;
        blkBase = tot ? atomicAdd(&candCount[b * 32], tot) : 0u;
    }
    __syncthreads();
    u32 run = blkBase + wsum[wave];
    u64* cb = cand + (size_t)b * CAP;
    #pragma unroll
    for (int it = 0; it < CITER; ++it) {
        u32 key = keys[it];
        bool pred = (key >> 10) >= thr;
        u64 m = __ballot(pred);
        if (pred) {
            u32 pos = run + (u32)__popcll(m & ((1ull << lane) - 1ull));
            u32 gi = base + it * 256 + tid;
            if (pos < CAP) cb[pos] = ((u64)key << 32) | (u32)(~gi);
        }
        run += (u32)__popcll(m);
    }
}

__global__ __launch_bounds__(512) void k_rank(const u64* __restrict__ cand,
                                              const u32* __restrict__ candCount,
                                              u64* __restrict__ sorted) {
    __shared__ u64 keys[CAP];
    int b = blockIdx.y;
    int tid = threadIdx.x;
    int cnt = (int)candCount[b * 32];
    if (cnt > CAP) cnt = CAP;
    const u64* cb = cand + (size_t)b * CAP;
    for (int j = tid; j < CAP; j += 512)
        keys[j] = (j < cnt) ? cb[j] : 0ull;
    __syncthreads();
    int r = blockIdx.x * 512 + tid;
    if (r >= cnt) return;
    u64 my = keys[r];
    int cnt16 = (cnt + 15) & ~15;
    int rank = 0;
    for (int j = 0; j < cnt16; j += 16) {
        #pragma unroll
        for (int u = 0; u < 16; ++u)
            rank += (keys[j + u] > my) ? 1 : 0;
    }
    if (rank < KSEL) sorted[(size_t)b * KSEL + rank] = my;
}

__global__ void k_decode(const u64* __restrict__ sorted,
                         const float4* __restrict__ anchors, const float4* __restrict__ deltas,
                         float4* __restrict__ boxes) {
    int b = blockIdx.y;
    int t = blockIdx.x * 256 + threadIdx.x;
    if (t >= KSEL) return;
    u64 sk = sorted[(size_t)b * KSEL + t];
    u32 idx = ~(u32)(sk & 0xFFFFFFFFull);
    if (idx >= NN) idx = NN - 1;
    float4 a = anchors[(size_t)b * NN + idx];
    float4 d = deltas[(size_t)b * NN + idx];
    float dy = __fmul_rn(d.x, 0.1f);
    float dx = __fmul_rn(d.y, 0.1f);
    float dh = __fmul_rn(d.z, 0.2f);
    float dw = __fmul_rn(d.w, 0.2f);
    float h  = __fsub_rn(a.z, a.x);
    float w  = __fsub_rn(a.w, a.y);
    float cy = __fadd_rn(__fadd_rn(a.x, __fmul_rn(0.5f, h)), __fmul_rn(dy, h));
    float cx = __fadd_rn(__fadd_rn(a.y, __fmul_rn(0.5f, w)), __fmul_rn(dx, w));
    float h2 = __fmul_rn(h, expf(dh));
    float w2 = __fmul_rn(w, expf(dw));
    float y1 = __fsub_rn(cy, __fmul_rn(0.5f, h2));
    float x1 = __fsub_rn(cx, __fmul_rn(0.5f, w2));
    float y2 = __fadd_rn(y1, h2);
    float x2 = __fadd_rn(x1, w2);
    y1 = fminf(fmaxf(y1, 0.0f), 1.0f);
    x1 = fminf(fmaxf(x1, 0.0f), 1.0f);
    y2 = fminf(fmaxf(y2, 0.0f), 1.0f);
    x2 = fminf(fmaxf(x2, 0.0f), 1.0f);
    float4 out;
    out.x = y1; out.y = x1; out.z = y2; out.w = x2;
    boxes[(size_t)b * KSEL + t] = out;
}

__global__ void k_sortgather(const u64* __restrict__ cand, const u32* __restrict__ candCount,
                             const float4* __restrict__ anchors, const float4* __restrict__ deltas,
                             float4* __restrict__ boxes) {
    __shared__ u64 s[CAP];
    int b = blockIdx.x;
    int tid = threadIdx.x;
    u32 cnt = candCount[b * 32];
    if (cnt > CAP) cnt = CAP;
    for (int j = tid; j < CAP; j += 1024)
        s[j] = (j < (int)cnt) ? cand[(size_t)b * CAP + j] : 0ull;
    __syncthreads();
    for (int k = 2; k <= CAP; k <<= 1) {
        for (int j = k >> 1; j > 0; j >>= 1) {
            for (int idx = tid; idx < CAP; idx += 1024) {
                int l = idx ^ j;
                if (l > idx) {
                    u64 a = s[idx], c = s[l];
                    bool dir = ((idx & k) == 0);
                    if ((a < c) == dir) { s[idx] = c; s[l] = a; }
                }
            }
            __syncthreads();
        }
    }
    for (int t = tid; t < KSEL; t += 1024) {
        u64 sk = s[t];
        u32 idx = ~(u32)(sk & 0xFFFFFFFFull);
        float4 a = anchors[(size_t)b * NN + idx];
        float4 d = deltas[(size_t)b * NN + idx];
        float dy = __fmul_rn(d.x, 0.1f);
        float dx = __fmul_rn(d.y, 0.1f);
        float dh = __fmul_rn(d.z, 0.2f);
        float dw = __fmul_rn(d.w, 0.2f);
        float h  = __fsub_rn(a.z, a.x);
        float w  = __fsub_rn(a.w, a.y);
        float cy = __fadd_rn(__fadd_rn(a.x, __fmul_rn(0.5f, h)), __fmul_rn(dy, h));
        float cx = __fadd_rn(__fadd_rn(a.y, __fmul_rn(0.5f, w)), __fmul_rn(dx, w));
        float h2 = __fmul_rn(h, expf(dh));
        float w2 = __fmul_rn(w, expf(dw));
        float y1 = __fsub_rn(cy, __fmul_rn(0.5f, h2));
        float x1 = __fsub_rn(cx, __fmul_rn(0.5f, w2));
        float y2 = __fadd_rn(y1, h2);
        float x2 = __fadd_rn(x1, w2);
        y1 = fminf(fmaxf(y1, 0.0f), 1.0f);
        x1 = fminf(fmaxf(x1, 0.0f), 1.0f);
        y2 = fminf(fmaxf(y2, 0.0f), 1.0f);
        x2 = fminf(fmaxf(x2, 0.0f), 1.0f);
        float4 out;
        out.x = y1; out.y = x1; out.z = y2; out.w = x2;
        boxes[(size_t)b * KSEL + t] = out;
    }
}

// ---------- phase 1: upper-triangle bitmask, row-major, stride NWP ----------
__global__ __launch_bounds__(256) void k_iou(const float4* __restrict__ boxes,
                                             u64* __restrict__ mask) {
    __shared__ float4 colBox[4][64];
    __shared__ float  colArea[4][64];
    int b = blockIdx.z;
    int rblk = blockIdx.x;
    int r0 = rblk * 64;
    int tid = threadIdx.x;
    int wave = tid >> 6, lane = tid & 63;
    const float4* B4 = boxes + (size_t)b * KSEL;

    int r = r0 + lane;
    float4 rb;
    if (r < KSEL) rb = B4[r];
    else { rb.x = 2.0f; rb.y = 2.0f; rb.z = 3.0f; rb.w = 3.0f; }
    float ra = __fmul_rn(__fsub_rn(rb.z, rb.x), __fsub_rn(rb.w, rb.y));

    const double M0 = 0.5 * ((double)__uint_as_float(0x3F333333u)
                           + (double)__uint_as_float(0x3F333334u));
    u64* Mb = mask + (size_t)b * NR * NWP;

    for (int jw = rblk + blockIdx.y * 4 + wave; jw < NW; jw += 4 * COLSPLIT) {
        int j = jw * 64 + lane;
        float4 cbx;
        if (j < KSEL) cbx = B4[j];
        else { cbx.x = 2.0f; cbx.y = 2.0f; cbx.z = 3.0f; cbx.w = 3.0f; }
        colBox[wave][lane] = cbx;
        colArea[wave][lane] = __fmul_rn(__fsub_rn(cbx.z, cbx.x), __fsub_rn(cbx.w, cbx.y));
        asm volatile("" ::: "memory");

        u64 word = 0ull;
        #pragma unroll
        for (int c = 0; c < 64; ++c) {
            float4 cb = colBox[wave][c];
            float ca = colArea[wave][c];
            float ih = fmaxf(__fsub_rn(fminf(rb.z, cb.z), fmaxf(rb.x, cb.x)), 0.0f);
            float iw = fmaxf(__fsub_rn(fminf(rb.w, cb.w), fmaxf(rb.y, cb.y)), 0.0f);
            float inter = __fmul_rn(ih, iw);
            float denom = __fadd_rn(__fsub_rn(__fadd_rn(ra, ca), inter), 1e-8f);
            bool pred = ((double)inter >= M0 * (double)denom);
            word |= ((u64)pred) << c;
        }
        Mb[(size_t)(r0 + lane) * NWP + jw] = word;
        asm volatile("" ::: "memory");
    }
}

// ---------- phase 2: 8-wave reduce, single-wave DECIDE + LDS broadcast ----------
// Same proven structure as R14, two changes:
// (1) DECIDE runs in wave 0 ONLY (uniform chain was redundantly executed by
//     all 8 waves, serializing 2x on shared SIMDs); kb,k broadcast via LDS at
//     the existing barrier. Race-free: pub reads (wave0, pre-barrier-1) vs pub
//     writes (post-barrier-1) ordered; kb write pre-barrier-1, reads after.
// (2) readfirstlane on rem to steer the uniform 64-bit chain toward SALU.
__device__ __forceinline__ u64 readlane64(u64 v, int lane) {
    u32 lo = (u32)__builtin_amdgcn_readlane((int)(u32)v, lane);
    u32 hi = (u32)__builtin_amdgcn_readlane((int)(u32)(v >> 32), lane);
    return ((u64)hi << 32) | (u64)lo;
}
__device__ __forceinline__ u64 rfl64(u64 v) {
    u32 lo = (u32)__builtin_amdgcn_readfirstlane((int)(u32)v);
    u32 hi = (u32)__builtin_amdgcn_readfirstlane((int)(u32)(v >> 32));
    return ((u64)hi << 32) | (u64)lo;
}

__global__ __launch_bounds__(512) void k_reduce(const u64* __restrict__ mask,
                                                const float4* __restrict__ boxes,
                                                float* __restrict__ outp) {
    __shared__ u64 pub[8];
    __shared__ u64 kbLDS;
    __shared__ u32 kLDS;
    __shared__ u32 keptIdx[PC];
    int b = blockIdx.x;
    int tid = threadIdx.x;
    int wv = tid >> 6, lane = tid & 63;
    const u64* M = mask + (size_t)b * NR * NWP;
    const float4* B4 = boxes + (size_t)b * KSEL;
    int lp = lane < 46 ? lane : 46;     // words 2lp,2lp+1 <= 93: no pad reads
    u64 rwA = 0ull, rwB = 0ull;
    int k = 0, kprev = 0;

    if (tid < 8) pub[tid] = 0ull;

    ulonglong2 cur[8], mid[8], nxt[8];
    u64 dgCur, dgMid, dgNxt;
    #pragma unroll
    for (int r = 0; r < 8; ++r) {
        cur[r] = *(const ulonglong2*)(M + (size_t)(wv * 8 + r) * NWP + 2 * lp);
        mid[r] = *(const ulonglong2*)(M + (size_t)(64 + wv * 8 + r) * NWP + 2 * lp);
    }
    dgCur = M[(size_t)lane * NWP + 0];
    dgMid = M[(size_t)(64 + lane) * NWP + 1];
    __syncthreads();   // pub init visible

    for (int g = 0; g < NW; ++g) {
        // prefetch group g+2
        int gn = (g + 2 < NW) ? g + 2 : NW - 1;
        #pragma unroll
        for (int r = 0; r < 8; ++r)
            nxt[r] = *(const ulonglong2*)(M + (size_t)(gn * 64 + wv * 8 + r) * NWP + 2 * lp);
        dgNxt = M[(size_t)(gn * 64 + lane) * NWP + gn];

        if (wv == 0) {
            // DECIDE(g), wave 0 only
            u64 rem = pub[0] | pub[1] | pub[2] | pub[3] | pub[4] | pub[5] | pub[6] | pub[7];
            rem = rfl64(rem);
            int remaining = KSEL - g * 64;
            u64 valid = (remaining >= 64) ? ~0ull : ((1ull << remaining) - 1ull);
            u64 todo = ~rem & valid;
            u64 kb0 = 0ull;
            int k0 = k;
            while (todo && k0 < PC) {
                int i = (int)__builtin_ctzll(todo);
                kb0 |= (1ull << i);
                ++k0;
                u64 drow = __ballot((dgCur >> i) & 1ull);   // row i's word via symmetry
                todo &= ~(drow | (1ull << i));
            }
            if ((kb0 >> lane) & 1ull) {
                int rank = kprev + (int)__popcll(kb0 & ((1ull << lane) - 1ull));
                keptIdx[rank] = (u32)(g * 64 + lane);
            }
            kprev = k0;
            if (lane == 0) { kbLDS = kb0; kLDS = (u32)k0; }
        }
        __syncthreads();                 // (1) kb,k visible; pub reads done
        u64 kb = kbLDS;
        k = (int)kLDS;

        // ACCUM kept rows of group g into this wave's partials
        #pragma unroll
        for (int r = 0; r < 8; ++r)
            if ((kb >> (wv * 8 + r)) & 1ull) { rwA |= cur[r].x; rwB |= cur[r].y; }

        if (k >= PC || g == NW - 1) break;   // uniform

        // publish word g+1 (wave-uniform value)
        int nw_ = g + 1;
        u64 wpub = (nw_ & 1) ? readlane64(rwB, nw_ >> 1) : readlane64(rwA, nw_ >> 1);
        if (lane == 0) pub[wv] = wpub;

        #pragma unroll
        for (int r = 0; r < 8; ++r) { cur[r] = mid[r]; mid[r] = nxt[r]; }
        dgCur = dgMid; dgMid = dgNxt;
        __syncthreads();                 // (2) publish visible for group g+1
    }
    __syncthreads();   // keptIdx visible to all threads

    float4* O = (float4*)outp + (size_t)b * PC;
    for (int t = tid; t < PC; t += 512) {
        float4 v; v.x = 0.0f; v.y = 0.0f; v.z = 0.0f; v.w = 0.0f;
        if (t < k) v = B4[keptIdx[t]];
        O[t] = v;
    }
}

// ---------- fallback serial NMS (used only if ws too small for mask) ----------
__global__ void k_nms(const float4* __restrict__ boxes, float* __restrict__ outp) {
    __shared__ float4 chunk[512];
    __shared__ float4 keptBox[PC];
    __shared__ float  keptArea[PC];
    __shared__ u32    flag[2];
    int b = blockIdx.x;
    int tid = threadIdx.x;
    const float4* B4 = boxes + (size_t)b * KSEL;

    if (tid < 2) flag[tid] = 0u;
    for (int j = tid; j < 512; j += 256) chunk[j] = B4[j];
    __syncthreads();

    int kc = 0;
    for (int i = 0; i < KSEL && kc < PC; ++i) {
        int ci = i & 511;
        if (ci == 0 && i != 0) {
            for (int j = tid; j < 512 && (i + j) < KSEL; j += 256) chunk[j] = B4[i + j];
            __syncthreads();
        }
        float4 cb = chunk[ci];
        float careaV = __fmul_rn(__fsub_rn(cb.z, cb.x), __fsub_rn(cb.w, cb.y));
        bool sup = false;
        for (int t = tid; t < kc; t += 256) {
            float4 kb2 = keptBox[t];
            float ih = fmaxf(__fsub_rn(fminf(cb.z, kb2.z), fmaxf(cb.x, kb2.x)), 0.0f);
            float iw = fmaxf(__fsub_rn(fminf(cb.w, kb2.w), fmaxf(cb.y, kb2.y)), 0.0f);
            float inter = __fmul_rn(ih, iw);
            float denom = __fadd_rn(__fsub_rn(__fadd_rn(careaV, keptArea[t]), inter), 1e-8f);
            if (__fdiv_rn(inter, denom) > NMS_THR) sup = true;
        }
        int p = i & 1;
        if (sup) flag[p] = 1u;
        if (tid == 0) flag[p ^ 1] = 0u;
        __syncthreads();
        if (flag[p] == 0u) {
            if (tid == 0) { keptBox[kc] = cb; keptArea[kc] = careaV; }
            kc++;
        }
        __syncthreads();
    }

    float4* out4 = (float4*)outp + (size_t)b * PC;
    for (int r = tid; r < PC; r += 256) {
        float4 v;
        if (r < kc) v = keptBox[r];
        else { v.x = 0.0f; v.y = 0.0f; v.z = 0.0f; v.w = 0.0f; }
        out4[r] = v;
    }
}

extern "C" void kernel_launch(void* const* d_in, const int* in_sizes, int n_in,
                              void* d_out, int out_size, void* d_ws, size_t ws_size,
                              hipStream_t stream) {
    const float* probs   = (const float*)d_in[0];
    const float* deltas  = (const float*)d_in[1];
    const float* anchors = (const float*)d_in[2];
    float* outp = (float*)d_out;

    u32* ws32 = (u32*)d_ws;
    u32* hist1 = ws32 + HIST1_OFF;
    u32* hist2 = ws32 + HIST2_OFF;
    u32* sel   = ws32 + SEL_OFF;
    u32* candCount = ws32 + CNT_OFF;
    u64* cand   = (u64*)(ws32 + ZERO_WORDS);
    u64* sorted = cand + (size_t)BB * CAP;
    float* boxesF = (float*)(sorted + (size_t)BB * KSEL);
    float4* boxes = (float4*)boxesF;
    u64* mask = (u64*)(boxesF + (size_t)BB * KSEL * 4);

    size_t needed = (size_t)ZERO_WORDS * 4 + (size_t)BB * CAP * 8 + (size_t)BB * KSEL * 8
                  + (size_t)BB * KSEL * 16 + (size_t)BB * NR * NWP * 8;

    hipLaunchKernelGGL(k_zero, dim3((ZERO_WORDS + 255) / 256), dim3(256), 0, stream, ws32);
    hipLaunchKernelGGL(k_hist1, dim3(HB, BB), dim3(256), 0, stream, (const float2*)probs, hist1);
    hipLaunchKernelGGL(k_sel1, dim3(BB), dim3(256), 0, stream, hist1, sel);
    hipLaunchKernelGGL(k_hist2, dim3(HB, BB), dim3(256), 0, stream, (const float2*)probs, sel, hist2);
    hipLaunchKernelGGL(k_sel2, dim3(BB), dim3(256), 0, stream, hist2, sel);
    hipLaunchKernelGGL(k_compact, dim3(CB, BB), dim3(256), 0, stream, (const float2*)probs, sel, candCount, cand);
    if (ws_size >= needed) {
        hipLaunchKernelGGL(k_rank, dim3(CAP / 512, BB), dim3(512), 0, stream, cand, candCount, sorted);
        hipLaunchKernelGGL(k_decode, dim3((KSEL + 255) / 256, BB), dim3(256), 0, stream,
                           sorted, (const float4*)anchors, (const float4*)deltas, boxes);
        hipLaunchKernelGGL(k_iou, dim3(NW, COLSPLIT, BB), dim3(256), 0, stream, boxes, mask);
        hipLaunchKernelGGL(k_reduce, dim3(BB), dim3(512), 0, stream, mask, boxes, outp);
    } else {
        hipLaunchKernelGGL(k_sortgather, dim3(BB), dim3(1024), 0, stream,
                           cand, candCount, (const float4*)anchors, (const float4*)deltas, boxes);
        hipLaunchKernelGGL(k_nms, dim3(BB), dim3(256), 0, stream, boxes, outp);
    }
}

// Round 17
// 214.110 us; speedup vs baseline: 1.3986x; 1.2189x over previous
//
#include <hip/hip_runtime.h>

typedef unsigned int u32;
typedef unsigned long long u64;

#define BB 4
#define NN 261888
#define KSEL 6000
#define CAP 8192
#define PC 1000
#define NMS_THR 0.7f
#define NW 94          /* words used */
#define NWP 96         /* padded row stride in words (768B rows, 16B aligned) */
#define NR (NW*64)     /* padded mask rows = 6016 */
#define COLSPLIT 6

#define HB 31
#define CHUNK_H (NN/HB)
#define HITER (CHUNK_H/256)
#define CB 93
#define CHUNK_C (NN/CB)
#define CITER (CHUNK_C/256)

#define CS 4             /* k_rank column slices */
#define CPS (CAP/CS)     /* 2048 columns per slice */

// ---------------- ws layout (u32 units) ----------------
// hist1 | hist2 | sel | candCount(128B-padded) | rankArr(BB*CAP u32) ... all zeroed
// then: cand(u64) | sorted(u64) | boxes(f32) | mask(u64, stride NWP)
#define HIST1_OFF 0
#define HIST2_OFF (BB*2048)
#define SEL_OFF   (BB*2048*2)
#define CNT_OFF   (BB*2048*2 + BB*4)
#define RANK_OFF  (BB*2048*2 + BB*4 + BB*32)
#define ZERO_WORDS (BB*2048*2 + BB*4 + BB*32 + BB*CAP)

__global__ void k_zero(u32* ws) {
    int i = blockIdx.x * 256 + threadIdx.x;
    if (i < ZERO_WORDS) ws[i] = 0u;
}

__global__ void k_hist1(const float2* __restrict__ probs2, u32* __restrict__ hist1) {
    __shared__ u32 lh[2048];
    int b = blockIdx.y;
    size_t base = (size_t)b * NN + (size_t)blockIdx.x * CHUNK_H;
    for (int j = threadIdx.x; j < 2048; j += 256) lh[j] = 0u;
    __syncthreads();
    #pragma unroll 4
    for (int it = 0; it < HITER; ++it) {
        float2 p = probs2[base + it * 256 + threadIdx.x];
        atomicAdd(&lh[__float_as_uint(p.y) >> 21], 1u);
    }
    __syncthreads();
    for (int j = threadIdx.x; j < 2048; j += 256) {
        u32 c = lh[j];
        if (c) atomicAdd(&hist1[b * 2048 + j], c);
    }
}

__global__ void k_sel1(const u32* __restrict__ hist1, u32* __restrict__ sel) {
    __shared__ u32 gsum[256];
    __shared__ u32 lh[2048];
    int b = blockIdx.x;
    int t = threadIdx.x;
    u32 s = 0;
    #pragma unroll
    for (int j = 0; j < 8; ++j) {
        u32 v = hist1[b * 2048 + 2047 - (t * 8 + j)];
        lh[t * 8 + j] = v;
        s += v;
    }
    gsum[t] = s;
    __syncthreads();
    if (t == 0) {
        u32 cum = 0;
        for (int g = 0; g < 256; ++g) {
            if (cum + gsum[g] >= (u32)KSEL) {
                for (int j = 0; j < 8; ++j) {
                    u32 c = lh[g * 8 + j];
                    if (cum + c >= (u32)KSEL) {
                        sel[b * 4 + 0] = (u32)(2047 - (g * 8 + j));
                        sel[b * 4 + 1] = cum;
                        break;
                    }
                    cum += c;
                }
                break;
            }
            cum += gsum[g];
        }
    }
}

__global__ void k_hist2(const float2* __restrict__ probs2, const u32* __restrict__ sel,
                        u32* __restrict__ hist2) {
    int b = blockIdx.y;
    u32 b1 = sel[b * 4 + 0];
    size_t base = (size_t)b * NN + (size_t)blockIdx.x * CHUNK_H;
    #pragma unroll 4
    for (int it = 0; it < HITER; ++it) {
        float2 p = probs2[base + it * 256 + threadIdx.x];
        u32 key = __float_as_uint(p.y);
        if ((key >> 21) == b1) atomicAdd(&hist2[b * 2048 + ((key >> 10) & 2047u)], 1u);
    }
}

__global__ void k_sel2(const u32* __restrict__ hist2, u32* __restrict__ sel) {
    __shared__ u32 gsum[256];
    __shared__ u32 lh[2048];
    int b = blockIdx.x;
    int t = threadIdx.x;
    u32 s = 0;
    #pragma unroll
    for (int j = 0; j < 8; ++j) {
        u32 v = hist2[b * 2048 + 2047 - (t * 8 + j)];
        lh[t * 8 + j] = v;
        s += v;
    }
    gsum[t] = s;
    __syncthreads();
    if (t == 0) {
        u32 cum = sel[b * 4 + 1];
        u32 b1 = sel[b * 4 + 0];
        for (int g = 0; g < 256; ++g) {
            if (cum + gsum[g] >= (u32)KSEL) {
                for (int j = 0; j < 8; ++j) {
                    cum += lh[g * 8 + j];
                    if (cum >= (u32)KSEL) {
                        sel[b * 4 + 2] = (b1 << 11) | (u32)(2047 - (g * 8 + j));
                        break;
                    }
                }
                break;
            }
            cum += gsum[g];
        }
    }
}

__global__ void k_compact(const float2* __restrict__ probs2, const u32* __restrict__ sel,
                          u32* __restrict__ candCount, u64* __restrict__ cand) {
    __shared__ u32 wsum[4];
    __shared__ u32 blkBase;
    int b = blockIdx.y;
    int tid = threadIdx.x;
    int wave = tid >> 6, lane = tid & 63;
    u32 base = (u32)blockIdx.x * CHUNK_C;
    u32 thr = sel[b * 4 + 2];

    u32 keys[CITER];
    u32 cnt = 0;
    #pragma unroll
    for (int it = 0; it < CITER; ++it) {
        float2 p = probs2[(size_t)b * NN + base + it * 256 + tid];
        u32 key = __float_as_uint(p.y);
        keys[it] = key;
        cnt += ((key >> 10) >= thr) ? 1u : 0u;
    }
    #pragma unroll
    for (int off = 32; off; off >>= 1) cnt += __shfl_down(cnt, off);
    if (lane == 0) wsum[wave] = cnt;
    __syncthreads();
    if (tid == 0) {
        u32 w0 = wsum[0], w1 = wsum[1], w2 = wsum[2], w3 = wsum[3];
        u32 tot = w0 + w1 + w2 + w3;
        wsum[0] = 0; wsum[1] = w0; wsum[2] = w0 + w1; wsum[3] = w0 + w1 + w2;
        blkBase = tot ? atomicAdd(&candCount[b * 32], tot) : 0u;
    }
    __syncthreads();
    u32 run = blkBase + wsum[wave];
    u64* cb = cand + (size_t)b * CAP;
    #pragma unroll
    for (int it = 0; it < CITER; ++it) {
        u32 key = keys[it];
        bool pred = (key >> 10) >= thr;
        u64 m = __ballot(pred);
        if (pred) {
            u32 pos = run + (u32)__popcll(m & ((1ull << lane) - 1ull));
            u32 gi = base + it * 256 + tid;
            if (pos < CAP) cb[pos] = ((u64)key << 32) | (u32)(~gi);
        }
        run += (u32)__popcll(m);
    }
}

// ---------- rank: column-sliced partial rank, atomic accumulate ----------
// grid (CAP/512, CS, BB), 512 thr. Block caches a 2048-key column slice in
// LDS; each thread counts keys > my over the slice; one atomicAdd per row.
__global__ __launch_bounds__(512) void k_rank(const u64* __restrict__ cand,
                                              const u32* __restrict__ candCount,
                                              u32* __restrict__ rankArr) {
    __shared__ u64 keys[CPS];   // 16 KB
    int b = blockIdx.z;
    int c0 = blockIdx.y * CPS;
    int tid = threadIdx.x;
    int cnt = (int)candCount[b * 32];
    if (cnt > CAP) cnt = CAP;
    const u64* cb = cand + (size_t)b * CAP;
    for (int j = tid; j < CPS; j += 512)
        keys[j] = (c0 + j < cnt) ? cb[c0 + j] : 0ull;   // 0 never outranks a real key
    __syncthreads();
    int r = blockIdx.x * 512 + tid;
    if (r >= cnt) return;
    u64 my = cb[r];
    u32 rank = 0;
    for (int j = 0; j < CPS; j += 16) {
        #pragma unroll
        for (int u = 0; u < 16; ++u)
            rank += (keys[j + u] > my) ? 1u : 0u;
    }
    if (rank) atomicAdd(&rankArr[b * CAP + r], rank);
}

// ---------- scatter: sorted[rank] = key (ranks are a permutation) ----------
__global__ void k_scatter(const u64* __restrict__ cand, const u32* __restrict__ candCount,
                          const u32* __restrict__ rankArr, u64* __restrict__ sorted) {
    int b = blockIdx.y;
    int p = blockIdx.x * 256 + threadIdx.x;
    int cnt = (int)candCount[b * 32];
    if (cnt > CAP) cnt = CAP;
    if (p >= cnt) return;
    u32 rank = rankArr[b * CAP + p];
    if (rank < KSEL) sorted[(size_t)b * KSEL + rank] = cand[(size_t)b * CAP + p];
}

__global__ void k_decode(const u64* __restrict__ sorted,
                         const float4* __restrict__ anchors, const float4* __restrict__ deltas,
                         float4* __restrict__ boxes) {
    int b = blockIdx.y;
    int t = blockIdx.x * 256 + threadIdx.x;
    if (t >= KSEL) return;
    u64 sk = sorted[(size_t)b * KSEL + t];
    u32 idx = ~(u32)(sk & 0xFFFFFFFFull);
    if (idx >= NN) idx = NN - 1;
    float4 a = anchors[(size_t)b * NN + idx];
    float4 d = deltas[(size_t)b * NN + idx];
    float dy = __fmul_rn(d.x, 0.1f);
    float dx = __fmul_rn(d.y, 0.1f);
    float dh = __fmul_rn(d.z, 0.2f);
    float dw = __fmul_rn(d.w, 0.2f);
    float h  = __fsub_rn(a.z, a.x);
    float w  = __fsub_rn(a.w, a.y);
    float cy = __fadd_rn(__fadd_rn(a.x, __fmul_rn(0.5f, h)), __fmul_rn(dy, h));
    float cx = __fadd_rn(__fadd_rn(a.y, __fmul_rn(0.5f, w)), __fmul_rn(dx, w));
    float h2 = __fmul_rn(h, expf(dh));
    float w2 = __fmul_rn(w, expf(dw));
    float y1 = __fsub_rn(cy, __fmul_rn(0.5f, h2));
    float x1 = __fsub_rn(cx, __fmul_rn(0.5f, w2));
    float y2 = __fadd_rn(y1, h2);
    float x2 = __fadd_rn(x1, w2);
    y1 = fminf(fmaxf(y1, 0.0f), 1.0f);
    x1 = fminf(fmaxf(x1, 0.0f), 1.0f);
    y2 = fminf(fmaxf(y2, 0.0f), 1.0f);
    x2 = fminf(fmaxf(x2, 0.0f), 1.0f);
    float4 out;
    out.x = y1; out.y = x1; out.z = y2; out.w = x2;
    boxes[(size_t)b * KSEL + t] = out;
}

__global__ void k_sortgather(const u64* __restrict__ cand, const u32* __restrict__ candCount,
                             const float4* __restrict__ anchors, const float4* __restrict__ deltas,
                             float4* __restrict__ boxes) {
    __shared__ u64 s[CAP];
    int b = blockIdx.x;
    int tid = threadIdx.x;
    u32 cnt = candCount[b * 32];
    if (cnt > CAP) cnt = CAP;
    for (int j = tid; j < CAP; j += 1024)
        s[j] = (j < (int)cnt) ? cand[(size_t)b * CAP + j] : 0ull;
    __syncthreads();
    for (int k = 2; k <= CAP; k <<= 1) {
        for (int j = k >> 1; j > 0; j >>= 1) {
            for (int idx = tid; idx < CAP; idx += 1024) {
                int l = idx ^ j;
                if (l > idx) {
                    u64 a = s[idx], c = s[l];
                    bool dir = ((idx & k) == 0);
                    if ((a < c) == dir) { s[idx] = c; s[l] = a; }
                }
            }
            __syncthreads();
        }
    }
    for (int t = tid; t < KSEL; t += 1024) {
        u64 sk = s[t];
        u32 idx = ~(u32)(sk & 0xFFFFFFFFull);
        float4 a = anchors[(size_t)b * NN + idx];
        float4 d = deltas[(size_t)b * NN + idx];
        float dy = __fmul_rn(d.x, 0.1f);
        float dx = __fmul_rn(d.y, 0.1f);
        float dh = __fmul_rn(d.z, 0.2f);
        float dw = __fmul_rn(d.w, 0.2f);
        float h  = __fsub_rn(a.z, a.x);
        float w  = __fsub_rn(a.w, a.y);
        float cy = __fadd_rn(__fadd_rn(a.x, __fmul_rn(0.5f, h)), __fmul_rn(dy, h));
        float cx = __fadd_rn(__fadd_rn(a.y, __fmul_rn(0.5f, w)), __fmul_rn(dx, w));
        float h2 = __fmul_rn(h, expf(dh));
        float w2 = __fmul_rn(w, expf(dw));
        float y1 = __fsub_rn(cy, __fmul_rn(0.5f, h2));
        float x1 = __fsub_rn(cx, __fmul_rn(0.5f, w2));
        float y2 = __fadd_rn(y1, h2);
        float x2 = __fadd_rn(x1, w2);
        y1 = fminf(fmaxf(y1, 0.0f), 1.0f);
        x1 = fminf(fmaxf(x1, 0.0f), 1.0f);
        y2 = fminf(fmaxf(y2, 0.0f), 1.0f);
        x2 = fminf(fmaxf(x2, 0.0f), 1.0f);
        float4 out;
        out.x = y1; out.y = x1; out.z = y2; out.w = x2;
        boxes[(size_t)b * KSEL + t] = out;
    }
}

// ---------- phase 1: upper-triangle bitmask, row-major, stride NWP ----------
__global__ __launch_bounds__(256) void k_iou(const float4* __restrict__ boxes,
                                             u64* __restrict__ mask) {
    __shared__ float4 colBox[4][64];
    __shared__ float  colArea[4][64];
    int b = blockIdx.z;
    int rblk = blockIdx.x;
    int r0 = rblk * 64;
    int tid = threadIdx.x;
    int wave = tid >> 6, lane = tid & 63;
    const float4* B4 = boxes + (size_t)b * KSEL;

    int r = r0 + lane;
    float4 rb;
    if (r < KSEL) rb = B4[r];
    else { rb.x = 2.0f; rb.y = 2.0f; rb.z = 3.0f; rb.w = 3.0f; }
    float ra = __fmul_rn(__fsub_rn(rb.z, rb.x), __fsub_rn(rb.w, rb.y));

    const double M0 = 0.5 * ((double)__uint_as_float(0x3F333333u)
                           + (double)__uint_as_float(0x3F333334u));
    u64* Mb = mask + (size_t)b * NR * NWP;

    for (int jw = rblk + blockIdx.y * 4 + wave; jw < NW; jw += 4 * COLSPLIT) {
        int j = jw * 64 + lane;
        float4 cbx;
        if (j < KSEL) cbx = B4[j];
        else { cbx.x = 2.0f; cbx.y = 2.0f; cbx.z = 3.0f; cbx.w = 3.0f; }
        colBox[wave][lane] = cbx;
        colArea[wave][lane] = __fmul_rn(__fsub_rn(cbx.z, cbx.x), __fsub_rn(cbx.w, cbx.y));
        asm volatile("" ::: "memory");

        u64 word = 0ull;
        #pragma unroll
        for (int c = 0; c < 64; ++c) {
            float4 cb = colBox[wave][c];
            float ca = colArea[wave][c];
            float ih = fmaxf(__fsub_rn(fminf(rb.z, cb.z), fmaxf(rb.x, cb.x)), 0.0f);
            float iw = fmaxf(__fsub_rn(fminf(rb.w, cb.w), fmaxf(rb.y, cb.y)), 0.0f);
            float inter = __fmul_rn(ih, iw);
            float denom = __fadd_rn(__fsub_rn(__fadd_rn(ra, ca), inter), 1e-8f);
            bool pred = ((double)inter >= M0 * (double)denom);
            word |= ((u64)pred) << c;
        }
        Mb[(size_t)(r0 + lane) * NWP + jw] = word;
        asm volatile("" ::: "memory");
    }
}

// ---------- phase 2: 8-wave reduce, single-wave DECIDE + LDS broadcast ----------
__device__ __forceinline__ u64 readlane64(u64 v, int lane) {
    u32 lo = (u32)__builtin_amdgcn_readlane((int)(u32)v, lane);
    u32 hi = (u32)__builtin_amdgcn_readlane((int)(u32)(v >> 32), lane);
    return ((u64)hi << 32) | (u64)lo;
}
__device__ __forceinline__ u64 rfl64(u64 v) {
    u32 lo = (u32)__builtin_amdgcn_readfirstlane((int)(u32)v);
    u32 hi = (u32)__builtin_amdgcn_readfirstlane((int)(u32)(v >> 32));
    return ((u64)hi << 32) | (u64)lo;
}

__global__ __launch_bounds__(512) void k_reduce(const u64* __restrict__ mask,
                                                const float4* __restrict__ boxes,
                                                float* __restrict__ outp) {
    __shared__ u64 pub[8];
    __shared__ u64 kbLDS;
    __shared__ u32 kLDS;
    __shared__ u32 keptIdx[PC];
    int b = blockIdx.x;
    int tid = threadIdx.x;
    int wv = tid >> 6, lane = tid & 63;
    const u64* M = mask + (size_t)b * NR * NWP;
    const float4* B4 = boxes + (size_t)b * KSEL;
    int lp = lane < 46 ? lane : 46;     // words 2lp,2lp+1 <= 93: no pad reads
    u64 rwA = 0ull, rwB = 0ull;
    int k = 0, kprev = 0;

    if (tid < 8) pub[tid] = 0ull;

    ulonglong2 cur[8], mid[8], nxt[8];
    u64 dgCur, dgMid, dgNxt;
    #pragma unroll
    for (int r = 0; r < 8; ++r) {
        cur[r] = *(const ulonglong2*)(M + (size_t)(wv * 8 + r) * NWP + 2 * lp);
        mid[r] = *(const ulonglong2*)(M + (size_t)(64 + wv * 8 + r) * NWP + 2 * lp);
    }
    dgCur = M[(size_t)lane * NWP + 0];
    dgMid = M[(size_t)(64 + lane) * NWP + 1];
    __syncthreads();   // pub init visible

    for (int g = 0; g < NW; ++g) {
        int gn = (g + 2 < NW) ? g + 2 : NW - 1;
        #pragma unroll
        for (int r = 0; r < 8; ++r)
            nxt[r] = *(const ulonglong2*)(M + (size_t)(gn * 64 + wv * 8 + r) * NWP + 2 * lp);
        dgNxt = M[(size_t)(gn * 64 + lane) * NWP + gn];

        if (wv == 0) {
            u64 rem = pub[0] | pub[1] | pub[2] | pub[3] | pub[4] | pub[5] | pub[6] | pub[7];
            rem = rfl64(rem);
            int remaining = KSEL - g * 64;
            u64 valid = (remaining >= 64) ? ~0ull : ((1ull << remaining) - 1ull);
            u64 todo = ~rem & valid;
            u64 kb0 = 0ull;
            int k0 = k;
            while (todo && k0 < PC) {
                int i = (int)__builtin_ctzll(todo);
                kb0 |= (1ull << i);
                ++k0;
                u64 drow = __ballot((dgCur >> i) & 1ull);
                todo &= ~(drow | (1ull << i));
            }
            if ((kb0 >> lane) & 1ull) {
                int rank = kprev + (int)__popcll(kb0 & ((1ull << lane) - 1ull));
                keptIdx[rank] = (u32)(g * 64 + lane);
            }
            kprev = k0;
            if (lane == 0) { kbLDS = kb0; kLDS = (u32)k0; }
        }
        __syncthreads();
        u64 kb = kbLDS;
        k = (int)kLDS;

        #pragma unroll
        for (int r = 0; r < 8; ++r)
            if ((kb >> (wv * 8 + r)) & 1ull) { rwA |= cur[r].x; rwB |= cur[r].y; }

        if (k >= PC || g == NW - 1) break;

        int nw_ = g + 1;
        u64 wpub = (nw_ & 1) ? readlane64(rwB, nw_ >> 1) : readlane64(rwA, nw_ >> 1);
        if (lane == 0) pub[wv] = wpub;

        #pragma unroll
        for (int r = 0; r < 8; ++r) { cur[r] = mid[r]; mid[r] = nxt[r]; }
        dgCur = dgMid; dgMid = dgNxt;
        __syncthreads();
    }
    __syncthreads();

    float4* O = (float4*)outp + (size_t)b * PC;
    for (int t = tid; t < PC; t += 512) {
        float4 v; v.x = 0.0f; v.y = 0.0f; v.z = 0.0f; v.w = 0.0f;
        if (t < k) v = B4[keptIdx[t]];
        O[t] = v;
    }
}

// ---------- fallback serial NMS (used only if ws too small for mask) ----------
__global__ void k_nms(const float4* __restrict__ boxes, float* __restrict__ outp) {
    __shared__ float4 chunk[512];
    __shared__ float4 keptBox[PC];
    __shared__ float  keptArea[PC];
    __shared__ u32    flag[2];
    int b = blockIdx.x;
    int tid = threadIdx.x;
    const float4* B4 = boxes + (size_t)b * KSEL;

    if (tid < 2) flag[tid] = 0u;
    for (int j = tid; j < 512; j += 256) chunk[j] = B4[j];
    __syncthreads();

    int kc = 0;
    for (int i = 0; i < KSEL && kc < PC; ++i) {
        int ci = i & 511;
        if (ci == 0 && i != 0) {
            for (int j = tid; j < 512 && (i + j) < KSEL; j += 256) chunk[j] = B4[i + j];
            __syncthreads();
        }
        float4 cb = chunk[ci];
        float careaV = __fmul_rn(__fsub_rn(cb.z, cb.x), __fsub_rn(cb.w, cb.y));
        bool sup = false;
        for (int t = tid; t < kc; t += 256) {
            float4 kb2 = keptBox[t];
            float ih = fmaxf(__fsub_rn(fminf(cb.z, kb2.z), fmaxf(cb.x, kb2.x)), 0.0f);
            float iw = fmaxf(__fsub_rn(fminf(cb.w, kb2.w), fmaxf(cb.y, kb2.y)), 0.0f);
            float inter = __fmul_rn(ih, iw);
            float denom = __fadd_rn(__fsub_rn(__fadd_rn(careaV, keptArea[t]), inter), 1e-8f);
            if (__fdiv_rn(inter, denom) > NMS_THR) sup = true;
        }
        int p = i & 1;
        if (sup) flag[p] = 1u;
        if (tid == 0) flag[p ^ 1] = 0u;
        __syncthreads();
        if (flag[p] == 0u) {
            if (tid == 0) { keptBox[kc] = cb; keptArea[kc] = careaV; }
            kc++;
        }
        __syncthreads();
    }

    float4* out4 = (float4*)outp + (size_t)b * PC;
    for (int r = tid; r < PC; r += 256) {
        float4 v;
        if (r < kc) v = keptBox[r];
        else { v.x = 0.0f; v.y = 0.0f; v.z = 0.0f; v.w = 0.0f; }
        out4[r] = v;
    }
}

extern "C" void kernel_launch(void* const* d_in, const int* in_sizes, int n_in,
                              void* d_out, int out_size, void* d_ws, size_t ws_size,
                              hipStream_t stream) {
    const float* probs   = (const float*)d_in[0];
    const float* deltas  = (const float*)d_in[1];
    const float* anchors = (const float*)d_in[2];
    float* outp = (float*)d_out;

    u32* ws32 = (u32*)d_ws;
    u32* hist1 = ws32 + HIST1_OFF;
    u32* hist2 = ws32 + HIST2_OFF;
    u32* sel   = ws32 + SEL_OFF;
    u32* candCount = ws32 + CNT_OFF;
    u32* rankArr   = ws32 + RANK_OFF;
    u64* cand   = (u64*)(ws32 + ZERO_WORDS);
    u64* sorted = cand + (size_t)BB * CAP;
    float* boxesF = (float*)(sorted + (size_t)BB * KSEL);
    float4* boxes = (float4*)boxesF;
    u64* mask = (u64*)(boxesF + (size_t)BB * KSEL * 4);

    size_t needed = (size_t)ZERO_WORDS * 4 + (size_t)BB * CAP * 8 + (size_t)BB * KSEL * 8
                  + (size_t)BB * KSEL * 16 + (size_t)BB * NR * NWP * 8;

    hipLaunchKernelGGL(k_zero, dim3((ZERO_WORDS + 255) / 256), dim3(256), 0, stream, ws32);
    hipLaunchKernelGGL(k_hist1, dim3(HB, BB), dim3(256), 0, stream, (const float2*)probs, hist1);
    hipLaunchKernelGGL(k_sel1, dim3(BB), dim3(256), 0, stream, hist1, sel);
    hipLaunchKernelGGL(k_hist2, dim3(HB, BB), dim3(256), 0, stream, (const float2*)probs, sel, hist2);
    hipLaunchKernelGGL(k_sel2, dim3(BB), dim3(256), 0, stream, hist2, sel);
    hipLaunchKernelGGL(k_compact, dim3(CB, BB), dim3(256), 0, stream, (const float2*)probs, sel, candCount, cand);
    if (ws_size >= needed) {
        hipLaunchKernelGGL(k_rank, dim3(CAP / 512, CS, BB), dim3(512), 0, stream, cand, candCount, rankArr);
        hipLaunchKernelGGL(k_scatter, dim3(CAP / 256, BB), dim3(256), 0, stream, cand, candCount, rankArr, sorted);
        hipLaunchKernelGGL(k_decode, dim3((KSEL + 255) / 256, BB), dim3(256), 0, stream,
                           sorted, (const float4*)anchors, (const float4*)deltas, boxes);
        hipLaunchKernelGGL(k_iou, dim3(NW, COLSPLIT, BB), dim3(256), 0, stream, boxes, mask);
        hipLaunchKernelGGL(k_reduce, dim3(BB), dim3(512), 0, stream, mask, boxes, outp);
    } else {
        hipLaunchKernelGGL(k_sortgather, dim3(BB), dim3(1024), 0, stream,
                           cand, candCount, (const float4*)anchors, (const float4*)deltas, boxes);
        hipLaunchKernelGGL(k_nms, dim3(BB), dim3(256), 0, stream, boxes, outp);
    }
}